// Round 11
// baseline (289.252 us; speedup 1.0000x reference)
//
#include <hip/hip_runtime.h>
#include <hip/hip_bf16.h>

#define BB 2
#define NN 4096
#define CH 64

typedef __bf16 bf16x8 __attribute__((ext_vector_type(8)));
typedef float f32x4 __attribute__((ext_vector_type(4)));

__device__ __forceinline__ float lrelu(float v) { return fmaxf(v, 0.1f * v); }
__device__ __forceinline__ float tobf(const __hip_bfloat16& h) { return __bfloat162float(h); }

// canonical f32 input region offsets (element offsets within cn)
#define PC1_C 0
#define PC2_C 24576
#define F1_C 49152
#define F2_C 573440
#define K1_C 1097728
#define K2_C 1622016
#define WT11_C 2146304
#define BT11_C 2150400
#define WT22_C 2150464
#define BT22_C 2154560
#define WPOS_C 2154624
#define BPOS_C 2154816
#define WM1_C 2154880
#define BM1_C 2158976
#define WM2_C 2159040
#define BM2_C 2163136
#define CN_TOTAL 2163200

// fhl half offset (bf16 elements): fl mirror of fh
#define FHALF (2 * BB * NN * CH)

// ---- packed selection keys: (order-mapped f32 score, top 20 bits)<<12 | (4095-idx)
__device__ __forceinline__ unsigned fmap(float s) {
  unsigned u = __float_as_uint(s);
  return u ^ ((unsigned)((int)u >> 31) | 0x80000000u);
}

__device__ __forceinline__ unsigned umaxu(unsigned a, unsigned b) { return a > b ? a : b; }
__device__ __forceinline__ void casu(unsigned& a, unsigned& b) {
  unsigned mx = a > b ? a : b;
  unsigned mn = a > b ? b : a;
  a = mx; b = mn;
}

// bitonic-8 desc merge (input bitonic -> sorted desc)
__device__ __forceinline__ void bitonic8(unsigned bd[8]) {
  casu(bd[0], bd[4]); casu(bd[1], bd[5]); casu(bd[2], bd[6]); casu(bd[3], bd[7]);
  casu(bd[0], bd[2]); casu(bd[1], bd[3]); casu(bd[4], bd[6]); casu(bd[5], bd[7]);
  casu(bd[0], bd[1]); casu(bd[2], bd[3]); casu(bd[4], bd[5]); casu(bd[6], bd[7]);
}

// merge 4 new keys into sorted-desc-8 bd[] (branch-free)
__device__ __forceinline__ void merge4(unsigned bd[8], unsigned k0, unsigned k1,
                                       unsigned k2, unsigned k3) {
  casu(k0, k1); casu(k2, k3); casu(k0, k2); casu(k1, k3); casu(k1, k2);
  bd[4] = umaxu(bd[4], k3); bd[5] = umaxu(bd[5], k2);
  bd[6] = umaxu(bd[6], k1); bd[7] = umaxu(bd[7], k0);
  bitonic8(bd);
}

// top-8 of union of two sorted-desc-8 lists -> a[]
__device__ __forceinline__ void merge88(unsigned a[8], const unsigned b[8]) {
  a[0] = umaxu(a[0], b[7]); a[1] = umaxu(a[1], b[6]);
  a[2] = umaxu(a[2], b[5]); a[3] = umaxu(a[3], b[4]);
  a[4] = umaxu(a[4], b[3]); a[5] = umaxu(a[5], b[2]);
  a[6] = umaxu(a[6], b[1]); a[7] = umaxu(a[7], b[0]);
  bitonic8(a);
}

// cross-lane merge: a = top-8 of (a U partner(lane^m)'s a)
__device__ __forceinline__ void xmerge(unsigned a[8], int m) {
  unsigned t[8];
#pragma unroll
  for (int k = 0; k < 8; ++k) t[k] = (unsigned)__shfl_xor((int)a[k], m, 64);
  merge88(a, t);
}

// ---- dtype detector
__global__ void k_detect(const unsigned short* __restrict__ pc1raw, int* __restrict__ flag) {
  int lane = threadIdx.x;  // 64
  int bad = 0;
#pragma unroll
  for (int i = 0; i < 64; ++i) {
    unsigned short u = pc1raw[lane * 64 + i];
    int e = (u >> 7) & 0xFF;
    bad += (e >= 140) ? 1 : 0;  // |v| >= 2^13 or Inf/NaN
  }
#pragma unroll
  for (int s = 32; s; s >>= 1) bad += __shfl_xor(bad, s, 64);
  if (lane == 0) *flag = (bad > 16) ? 1 : 0;  // 1 = inputs are float32
}

// ---- ingest: convert all 16 inputs to canonical f32 + sanitize
__global__ __launch_bounds__(256) void k_ingest(
    const void* p0, const void* p1, const void* p2, const void* p3,
    const void* p4, const void* p5, const void* p6, const void* p7,
    const void* p8, const void* p9, const void* p10, const void* p11,
    const void* p12, const void* p13, const void* p14, const void* p15,
    const int* __restrict__ flag, float* __restrict__ dst) {
  const int cum[17] = {0, 24576, 49152, 573440, 1097728, 1622016, 2146304, 2150400,
                       2150464, 2154560, 2154624, 2154816, 2154880, 2158976, 2159040,
                       2163136, 2163200};
  size_t t = (size_t)blockIdx.x * 256 + threadIdx.x;
  if (t >= (size_t)CN_TOTAL) return;
  int seg = 0;
#pragma unroll
  for (int i = 1; i < 16; ++i) seg += (t >= (size_t)cum[i]) ? 1 : 0;
  size_t local = t - (size_t)cum[seg];
  const void* ptrs[16] = {p0, p1, p2, p3, p4, p5, p6, p7, p8, p9, p10, p11, p12, p13, p14, p15};
  const void* p = ptrs[seg];
  float v;
  if (*flag) v = ((const float*)p)[local];
  else       v = tobf(((const __hip_bfloat16*)p)[local]);
  if (!(v == v) || fabsf(v) > 1e30f) v = 0.f;  // sanitize (no-op on clean data)
  dst[t] = v;
}

// ---- fused prep (one launch, cn-based): knn-normalize, feat hi/lo, Wm->bf16,
// xyz float4, wpos, conv-W hi/lo.
__global__ __launch_bounds__(256) void k_prep_all(const float* __restrict__ cn,
                                                  float* __restrict__ knnt,
                                                  __hip_bfloat16* __restrict__ knnb,
                                                  __hip_bfloat16* __restrict__ fhl,
                                                  __hip_bfloat16* __restrict__ wmb,
                                                  float4* __restrict__ xyzt,
                                                  float4* __restrict__ wp4,
                                                  __hip_bfloat16* __restrict__ wcb) {
  int bid = blockIdx.x;
  if (bid < 64) {
    int t = bid * 256 + threadIdx.x;  // 2*BB*NN
    int n = t & (NN - 1);
    int b = (t >> 12) & 1;
    int a = t >> 13;
    const float* col = cn + (a ? K2_C : K1_C) + (size_t)b * CH * NN + n;
    float s = 0.f;
#pragma unroll
    for (int c = 0; c < CH; ++c) { float v = col[(size_t)c * NN]; s += v * v; }
    float inv = 1.0f / sqrtf(s + 1e-8f);
    size_t row = (size_t)(a * BB + b) * NN + n;
    float* o = knnt + row * CH;
    __hip_bfloat16* ob = knnb + row * CH;
#pragma unroll
    for (int c = 0; c < CH; ++c) {
      float v = col[(size_t)c * NN] * inv;
      o[c] = v;
      ob[c] = __float2bfloat16(v);
    }
  } else if (bid < 128) {
    int t = (bid - 64) * 256 + threadIdx.x;  // 2*BB*NN
    int n = t & (NN - 1);
    int b = (t >> 12) & 1;
    int a = t >> 13;
    const float* col = cn + (a ? F2_C : F1_C) + (size_t)b * CH * NN + n;
    __hip_bfloat16* oh = fhl + ((size_t)(a * BB + b) * NN + n) * CH;
    __hip_bfloat16* ol = oh + FHALF;
#pragma unroll
    for (int c = 0; c < CH; ++c) {
      float v = col[(size_t)c * NN];
      __hip_bfloat16 hi = __float2bfloat16(v);
      oh[c] = hi;
      ol[c] = __float2bfloat16(v - tobf(hi));
    }
  } else if (bid < 160) {
    int t = (bid - 128) * 256 + threadIdx.x;  // 8192
    float v = (t < 4096) ? cn[WM1_C + t] : cn[WM2_C + (t - 4096)];
    wmb[t] = __float2bfloat16(v);
  } else if (bid < 224) {
    int t = (bid - 160) * 256 + threadIdx.x;  // 2*BB*NN
    int n = t & (NN - 1);
    int b = (t >> 12) & 1;
    int a = t >> 13;
    const float* p = cn + (a ? PC2_C : PC1_C) + (size_t)b * 3 * NN + n;
    float x = p[0], y = p[NN], z = p[2 * NN];
    xyzt[(size_t)(a * BB + b) * NN + n] = make_float4(x, y, z, x * x + y * y + z * z);
  } else if (bid == 224) {
    int c = threadIdx.x;
    if (c < 64)
      wp4[c] = make_float4(cn[WPOS_C + 3 * c], cn[WPOS_C + 3 * c + 1],
                           cn[WPOS_C + 3 * c + 2], cn[BPOS_C + c]);
  } else {
    // conv weight hi/lo split: wcb[w][d*64+c] hi at [0,8192), lo at [8192,16384)
    int t = (bid - 225) * 256 + threadIdx.x;  // 8192 = 2 W x 4096
    int w = t >> 12, e = t & 4095;
    float v = cn[(w ? WT22_C : WT11_C) + e];
    __hip_bfloat16 hi = __float2bfloat16(v);
    __hip_bfloat16 lo = __float2bfloat16(v - tobf(hi));
    wcb[w * 4096 + e] = hi;
    wcb[8192 + w * 4096 + e] = lo;
  }
}

// ======================================================================
// R16 k_knncv: (1) __launch_bounds__ (512,4)->(512,6): the w=4 bound was
// itself capping residency at 2 blocks/CU (occupancy 41% with VGPR=52 and
// LDS=5.6KB that would allow 4); w=6 raises the target to 3 blocks/CU with
// VGPR budget ~85 > 52 (no spill risk -- R12's w=8 capped at 32 and spilled).
// (2) extraction restructured: dump BOTH key sets, ONE barrier, waves 0-3
// extract cosine / 4-7 euclid in parallel (4 queries/wave, 16-lane groups,
// bitonic-16). Same keys/top-16/exact-rescore/tie rules -> same results.
// ======================================================================
__global__ __launch_bounds__(512, 6) void k_knncv(const __hip_bfloat16* __restrict__ knnb,
                                                  const float* __restrict__ knnt,
                                                  const float4* __restrict__ xyzt,
                                                  const __hip_bfloat16* __restrict__ fhl,
                                                  const __hip_bfloat16* __restrict__ wcb,
                                                  const float* __restrict__ cn,
                                                  int* __restrict__ idxf,
                                                  float* __restrict__ fbuf) {
  int bid = blockIdx.x;
  if (bid >= 1024) {
    // ---------------- conv path (no barriers, early return) ----------------
    int cb = bid - 1024;  // 512: b(1) | a(1) | pair(7 high); ntile = pair*2 + (tid>>8)
    int b = cb & 1;
    int a = (cb >> 1) & 1;
    int ntile = (cb >> 2) * 2 + (threadIdx.x >> 8);
    int t = threadIdx.x & 255;
    int dt = t >> 6;
    int lane = t & 63;
    int lo = lane & 15, g = lane >> 4;

    const __hip_bfloat16* fb = fhl + ((size_t)(a * BB + b) * NN + ntile * 16 + lo) * CH;
    bf16x8 ah0 = *reinterpret_cast<const bf16x8*>(fb + g * 8);
    bf16x8 ah1 = *reinterpret_cast<const bf16x8*>(fb + 32 + g * 8);
    bf16x8 al0 = *reinterpret_cast<const bf16x8*>(fb + FHALF + g * 8);
    bf16x8 al1 = *reinterpret_cast<const bf16x8*>(fb + FHALF + 32 + g * 8);

#pragma unroll
    for (int w = 0; w < 2; ++w) {
      const __hip_bfloat16* wb = wcb + w * 4096 + (dt * 16 + lo) * 64;
      bf16x8 wh0 = *reinterpret_cast<const bf16x8*>(wb + g * 8);
      bf16x8 wh1 = *reinterpret_cast<const bf16x8*>(wb + 32 + g * 8);
      bf16x8 wl0 = *reinterpret_cast<const bf16x8*>(wb + 8192 + g * 8);
      bf16x8 wl1 = *reinterpret_cast<const bf16x8*>(wb + 8192 + 32 + g * 8);
      float bv = cn[(w ? BT22_C : BT11_C) + dt * 16 + lo];
      f32x4 acc = {bv, bv, bv, bv};
      acc = __builtin_amdgcn_mfma_f32_16x16x32_bf16(ah0, wh0, acc, 0, 0, 0);
      acc = __builtin_amdgcn_mfma_f32_16x16x32_bf16(ah1, wh1, acc, 0, 0, 0);
      acc = __builtin_amdgcn_mfma_f32_16x16x32_bf16(al0, wh0, acc, 0, 0, 0);
      acc = __builtin_amdgcn_mfma_f32_16x16x32_bf16(al1, wh1, acc, 0, 0, 0);
      acc = __builtin_amdgcn_mfma_f32_16x16x32_bf16(ah0, wl0, acc, 0, 0, 0);
      acc = __builtin_amdgcn_mfma_f32_16x16x32_bf16(ah1, wl1, acc, 0, 0, 0);
      int sel = a ? (w ? 1 : 2) : (w ? 3 : 0);
      float* ob = fbuf + ((size_t)(sel * BB + b) * NN + ntile * 16 + g * 4) * CH + dt * 16 + lo;
      ob[0 * CH] = acc[0];
      ob[1 * CH] = acc[1];
      ob[2 * CH] = acc[2];
      ob[3 * CH] = acc[3];
    }
    return;
  }

  // ---------------- knn path ----------------
  __shared__ unsigned skc[16 * 8 * 9];  // cosine keys, 4.6 KB
  __shared__ unsigned ske[16 * 8 * 9];  // euclid keys, 4.6 KB
  __shared__ int cidx[2 * 16 * 16];     // [phase][query][16 cand]
  int b = bid & 1;
  int x = (bid >> 1) & 1;
  int qt = bid >> 2;
  int w = threadIdx.x >> 6;
  int lane = threadIdx.x & 63;
  int lo = lane & 15, g = lane >> 4;
  int q0 = qt * 16;
  int j0 = w * (NN / 8);
  size_t qbase = (size_t)(x * BB + b) * NN;
  size_t dbase = (size_t)((1 - x) * BB + b) * NN;

  const __hip_bfloat16* qb = knnb + (qbase + q0) * CH;
  bf16x8 qf0 = *reinterpret_cast<const bf16x8*>(qb + lo * CH + g * 8);
  bf16x8 qf1 = *reinterpret_cast<const bf16x8*>(qb + lo * CH + 32 + g * 8);
  const __hip_bfloat16* db = knnb + dbase * CH;
  const float4 q4 = xyzt[qbase + q0 + lo];
  const float4* dbx = xyzt + dbase;
  float tx = 2.f * q4.x, ty = 2.f * q4.y, tz = 2.f * q4.z;

  unsigned bc0[8], bc1[8], be0[8], be1[8];
#pragma unroll
  for (int k = 0; k < 8; ++k) { bc0[k] = 0u; bc1[k] = 0u; be0[k] = 0u; be1[k] = 0u; }

  auto STEP = [&](const bf16x8& A0, const bf16x8& A1, const float4& P0,
                  const float4& P1, const float4& P2, const float4& P3,
                  int rcv, unsigned (&bc)[8], unsigned (&be)[8]) {
    f32x4 acc = {0.f, 0.f, 0.f, 0.f};
    acc = __builtin_amdgcn_mfma_f32_16x16x32_bf16(A0, qf0, acc, 0, 0, 0);
    acc = __builtin_amdgcn_mfma_f32_16x16x32_bf16(A1, qf1, acc, 0, 0, 0);
    float v0 = fmaf(tx, P0.x, fmaf(ty, P0.y, fmaf(tz, P0.z, -P0.w)));
    float v1 = fmaf(tx, P1.x, fmaf(ty, P1.y, fmaf(tz, P1.z, -P1.w)));
    float v2 = fmaf(tx, P2.x, fmaf(ty, P2.y, fmaf(tz, P2.z, -P2.w)));
    float v3 = fmaf(tx, P3.x, fmaf(ty, P3.y, fmaf(tz, P3.z, -P3.w)));
    unsigned r = (unsigned)rcv;
    merge4(bc, (__float_as_uint(acc[0] + 4.0f) & 0xFFFFF000u) | r,
               (__float_as_uint(acc[1] + 4.0f) & 0xFFFFF000u) | (r - 1),
               (__float_as_uint(acc[2] + 4.0f) & 0xFFFFF000u) | (r - 2),
               (__float_as_uint(acc[3] + 4.0f) & 0xFFFFF000u) | (r - 3));
    merge4(be, (fmap(v0) & 0xFFFFF000u) | r,
               (fmap(v1) & 0xFFFFF000u) | (r - 1),
               (fmap(v2) & 0xFFFFF000u) | (r - 2),
               (fmap(v3) & 0xFFFFF000u) | (r - 3));
  };

  // ---- pipelined scan: 32 tiles, A=even / B=odd, one-tile prefetch ahead
  const __hip_bfloat16* arA = db + (size_t)(j0 + lo) * CH + g * 8;
  const __hip_bfloat16* arB = arA + 16 * CH;
  const float4* peA = dbx + j0 + g * 4;
  const float4* peB = peA + 16;
  int rc = 4095 - j0 - g * 4;

  bf16x8 aA0 = *reinterpret_cast<const bf16x8*>(arA);
  bf16x8 aA1 = *reinterpret_cast<const bf16x8*>(arA + 32);
  float4 pA0 = peA[0], pA1 = peA[1], pA2 = peA[2], pA3 = peA[3];

  for (int i = 0; i < 15; ++i) {
    bf16x8 aB0 = *reinterpret_cast<const bf16x8*>(arB);
    bf16x8 aB1 = *reinterpret_cast<const bf16x8*>(arB + 32);
    float4 pB0 = peB[0], pB1 = peB[1], pB2 = peB[2], pB3 = peB[3];
    STEP(aA0, aA1, pA0, pA1, pA2, pA3, rc, bc0, be0);
    arA += 32 * CH; peA += 32;
    aA0 = *reinterpret_cast<const bf16x8*>(arA);
    aA1 = *reinterpret_cast<const bf16x8*>(arA + 32);
    pA0 = peA[0]; pA1 = peA[1]; pA2 = peA[2]; pA3 = peA[3];
    STEP(aB0, aB1, pB0, pB1, pB2, pB3, rc - 16, bc1, be1);
    arB += 32 * CH; peB += 32;
    rc -= 32;
  }
  {
    bf16x8 aB0 = *reinterpret_cast<const bf16x8*>(arB);
    bf16x8 aB1 = *reinterpret_cast<const bf16x8*>(arB + 32);
    float4 pB0 = peB[0], pB1 = peB[1], pB2 = peB[2], pB3 = peB[3];
    STEP(aA0, aA1, pA0, pA1, pA2, pA3, rc, bc0, be0);
    STEP(aB0, aB1, pB0, pB1, pB2, pB3, rc - 16, bc1, be1);
  }
  merge88(bc0, bc1);
  merge88(be0, be1);
  // cross-group register merge: 32 substreams -> 8 (one per wave, per query)
  xmerge(bc0, 16); xmerge(bc0, 32);
  xmerge(be0, 16); xmerge(be0, 32);

  // ---- dump BOTH phases' keys, one barrier
  if (g == 0) {
#pragma unroll
    for (int k = 0; k < 8; ++k) {
      skc[(lo * 8 + k) * 9 + w] = bc0[k];
      ske[(lo * 8 + k) * 9 + w] = be0[k];
    }
  }
  __syncthreads();

  // ---- unified extraction: waves 0-3 cosine, 4-7 euclid; 4 queries/wave,
  //      16-lane groups (slots duplicated x2 within group)
  {
    int p = w >> 2;                          // 0 = cosine, 1 = euclid
    int qq = (w & 3) * 4 + (lane >> 4);      // this group's query (0..15)
    int sl = lane & 15;
    const unsigned* skp = p ? ske : skc;
    unsigned e[16];
#pragma unroll
    for (int k = 0; k < 8; ++k) e[k] = skp[(qq * 8 + k) * 9 + (sl & 7)];
#pragma unroll
    for (int k = 8; k < 16; ++k) e[k] = 0u;
#pragma unroll
    for (int s = 1; s < 8; s <<= 1) {
      unsigned f[16];
#pragma unroll
      for (int k = 0; k < 16; ++k) f[k] = (unsigned)__shfl_xor((int)e[k], s, 64);
#pragma unroll
      for (int i = 0; i < 16; ++i) e[i] = umaxu(e[i], f[15 - i]);
      casu(e[0], e[8]); casu(e[1], e[9]); casu(e[2], e[10]); casu(e[3], e[11]);
      casu(e[4], e[12]); casu(e[5], e[13]); casu(e[6], e[14]); casu(e[7], e[15]);
      casu(e[0], e[4]); casu(e[1], e[5]); casu(e[2], e[6]); casu(e[3], e[7]);
      casu(e[8], e[12]); casu(e[9], e[13]); casu(e[10], e[14]); casu(e[11], e[15]);
      casu(e[0], e[2]); casu(e[1], e[3]); casu(e[4], e[6]); casu(e[5], e[7]);
      casu(e[8], e[10]); casu(e[9], e[11]); casu(e[12], e[14]); casu(e[13], e[15]);
      casu(e[0], e[1]); casu(e[2], e[3]); casu(e[4], e[5]); casu(e[6], e[7]);
      casu(e[8], e[9]); casu(e[10], e[11]); casu(e[12], e[13]); casu(e[14], e[15]);
    }
    if (sl == 0) {
#pragma unroll
      for (int k = 0; k < 16; ++k) cidx[(p * 16 + qq) * 16 + k] = 4095 - (int)(e[k] & 4095u);
    }
    int idx = cidx[(p * 16 + qq) * 16 + sl];  // same-wave lockstep write->read
    float v;
    if (p == 0) {
      // cosine: exact f32 dot of normalized rows (one lane per candidate)
      const float4* qr = reinterpret_cast<const float4*>(knnt + (qbase + q0 + qq) * CH);
      const float4* dr = reinterpret_cast<const float4*>(knnt + (dbase + idx) * CH);
      v = 0.f;
#pragma unroll 4
      for (int cb = 0; cb < 16; ++cb) {
        float4 qv = qr[cb], dv = dr[cb];
        v += qv.x * dv.x + qv.y * dv.y + qv.z * dv.z + qv.w * dv.w;
      }
    } else {
      // euclid: exact f32 key = 2*q.p - |p|^2
      const float4 qx4 = xyzt[qbase + q0 + qq];
      float4 pp = xyzt[dbase + idx];
      v = fmaf(2.f * qx4.x, pp.x, fmaf(2.f * qx4.y, pp.y, fmaf(2.f * qx4.z, pp.z, -pp.w)));
    }
    // bitonic sort 16 distinct candidates desc by (v, idx asc); take first 8
    int ii = idx;
#pragma unroll
    for (int k = 2; k <= 16; k <<= 1) {
#pragma unroll
      for (int j = k >> 1; j >= 1; j >>= 1) {
        float ov = __shfl_xor(v, j, 64);
        int oi = __shfl_xor(ii, j, 64);
        bool ob = (ov > v) || (ov == v && oi < ii);
        bool want = (((sl & k) == 0) == ((sl & j) == 0));
        bool take = (want == ob);
        v = take ? ov : v;
        ii = take ? oi : ii;
      }
    }
    if (sl < 8) idxf[(qbase + q0 + qq) * 16 + p * 8 + sl] = ii;
  }
}

// ---- fused gather + pos-conv + 2x MFMA MLP + neighbor max. One wave per query.
// XCD-aware decode (x,b in low bid bits).
__global__ __launch_bounds__(256) void k_mlp(const float* __restrict__ fbuf,
                                             const float4* __restrict__ xyzt,
                                             const int* __restrict__ idxf,
                                             const float4* __restrict__ wp4,
                                             const __hip_bfloat16* __restrict__ wmb,
                                             const float* __restrict__ cn,
                                             float* __restrict__ out) {
  __shared__ __bf16 h1s[4 * 16 * 72];  // per-wave 16 rows x stride 72
  const int t = threadIdx.x;
  const int wv = t >> 6, L = t & 63;
  const int lo = L & 15, g = L >> 4;
  int bid = blockIdx.x;  // 4096: b(1) | x(1) | qt(10 high)
  const int b = bid & 1;
  const int x = (bid >> 1) & 1;
  const int qt = bid >> 2;
  const int q = qt * 4 + wv;

  bf16x8 w1f[4][2], w2f[4][2];
#pragma unroll
  for (int tt = 0; tt < 4; ++tt)
#pragma unroll
    for (int kc = 0; kc < 2; ++kc) {
      int e = tt * 16 + lo, c0 = kc * 32 + g * 8;
      w1f[tt][kc] = *reinterpret_cast<const bf16x8*>(wmb + e * 64 + c0);
      w2f[tt][kc] = *reinterpret_cast<const bf16x8*>(wmb + 4096 + e * 64 + c0);
    }

  const float* pq  = fbuf + ((size_t)((x ? 2 : 0) * BB + b)) * NN * CH;
  const float* pdb = fbuf + ((size_t)((x ? 3 : 1) * BB + b)) * NN * CH;
  const float4* qx  = xyzt + (size_t)(x * BB + b) * NN;
  const float4* dbx = xyzt + (size_t)((1 - x) * BB + b) * NN;

  const int m = lo;
  int jm = idxf[(((size_t)x * BB + b) * NN + q) * 16 + m];
  jm &= (NN - 1);
  const float4 q4 = qx[q];
  const float4 p4 = dbx[jm];
  const float dx = p4.x - q4.x, dy = p4.y - q4.y, dz = p4.z - q4.z;

  const float4* g2v = reinterpret_cast<const float4*>(pdb + (size_t)jm * CH);
  const float4* pqv = reinterpret_cast<const float4*>(pq + (size_t)q * CH);
  float hv[16];
  {
    float4 t0 = g2v[g * 2], t1 = g2v[g * 2 + 1], t2 = g2v[g * 2 + 8], t3 = g2v[g * 2 + 9];
    float4 u0 = pqv[g * 2], u1 = pqv[g * 2 + 1], u2 = pqv[g * 2 + 8], u3 = pqv[g * 2 + 9];
    hv[0] = t0.x + u0.x; hv[1] = t0.y + u0.y; hv[2] = t0.z + u0.z; hv[3] = t0.w + u0.w;
    hv[4] = t1.x + u1.x; hv[5] = t1.y + u1.y; hv[6] = t1.z + u1.z; hv[7] = t1.w + u1.w;
    hv[8] = t2.x + u2.x; hv[9] = t2.y + u2.y; hv[10] = t2.z + u2.z; hv[11] = t2.w + u2.w;
    hv[12] = t3.x + u3.x; hv[13] = t3.y + u3.y; hv[14] = t3.z + u3.z; hv[15] = t3.w + u3.w;
  }

  bf16x8 a0, a1;
#pragma unroll
  for (int kc = 0; kc < 2; ++kc) {
#pragma unroll
    for (int j = 0; j < 8; ++j) {
      int c = kc * 32 + g * 8 + j;
      float4 wp = wp4[c];
      float v = hv[kc * 8 + j] + wp.x * dx + wp.y * dy + wp.z * dz + wp.w;
      v = lrelu(v);
      if (kc == 0) a0[j] = (__bf16)v; else a1[j] = (__bf16)v;
    }
  }

  __bf16* hrow = h1s + wv * 16 * 72;
#pragma unroll
  for (int tt = 0; tt < 4; ++tt) {
    float bv = cn[BM1_C + tt * 16 + lo];
    f32x4 acc = {bv, bv, bv, bv};
    acc = __builtin_amdgcn_mfma_f32_16x16x32_bf16(a0, w1f[tt][0], acc, 0, 0, 0);
    acc = __builtin_amdgcn_mfma_f32_16x16x32_bf16(a1, w1f[tt][1], acc, 0, 0, 0);
#pragma unroll
    for (int r = 0; r < 4; ++r) {
      float v = lrelu(acc[r]);
      hrow[(g * 4 + r) * 72 + tt * 16 + lo] = (__bf16)v;
    }
  }
  __syncthreads();
  bf16x8 h1a = *reinterpret_cast<const bf16x8*>(hrow + m * 72 + g * 8);
  bf16x8 h1b = *reinterpret_cast<const bf16x8*>(hrow + m * 72 + 32 + g * 8);

  size_t obase = ((size_t)(x * BB + b) * CH) * NN;
#pragma unroll
  for (int tt = 0; tt < 4; ++tt) {
    float bv = cn[BM2_C + tt * 16 + lo];
    f32x4 acc = {bv, bv, bv, bv};
    acc = __builtin_amdgcn_mfma_f32_16x16x32_bf16(h1a, w2f[tt][0], acc, 0, 0, 0);
    acc = __builtin_amdgcn_mfma_f32_16x16x32_bf16(h1b, w2f[tt][1], acc, 0, 0, 0);
    float v = fmaxf(fmaxf(lrelu(acc[0]), lrelu(acc[1])), fmaxf(lrelu(acc[2]), lrelu(acc[3])));
    v = fmaxf(v, __shfl_xor(v, 16, 64));
    v = fmaxf(v, __shfl_xor(v, 32, 64));
    if (g == 0) out[obase + (size_t)(tt * 16 + lo) * NN + q] = v;
  }
}

// workspace layout (float units)
#define CN_OFF 0
#define FB_OFF ((size_t)CN_TOTAL)
#define KT_OFF (FB_OFF + (size_t)4 * BB * NN * CH)
#define XZ_OFF (KT_OFF + (size_t)2 * BB * NN * CH)
#define WP4_OFF (XZ_OFF + (size_t)2 * BB * NN * 4)
#define WMB_OFF (WP4_OFF + 256)
#define IDX_OFF (WMB_OFF + 4096)
#define FLAG_OFF (IDX_OFF + 262144)
#define KNB_OFF (FLAG_OFF + 4)
#define FHL_OFF (KNB_OFF + (size_t)BB * NN * CH)
#define WCB_OFF (FHL_OFF + (size_t)2 * BB * NN * CH)

extern "C" void kernel_launch(void* const* d_in, const int* in_sizes, int n_in,
                              void* d_out, int out_size, void* d_ws, size_t ws_size,
                              hipStream_t stream) {
  float* ws = (float*)d_ws;
  float* cn = ws + CN_OFF;
  int* flag = (int*)(ws + FLAG_OFF);

  k_detect<<<1, 64, 0, stream>>>((const unsigned short*)d_in[0], flag);
  k_ingest<<<(CN_TOTAL + 255) / 256, 256, 0, stream>>>(
      d_in[0], d_in[1], d_in[2], d_in[3], d_in[4], d_in[5], d_in[6], d_in[7],
      d_in[8], d_in[9], d_in[10], d_in[11], d_in[12], d_in[13], d_in[14], d_in[15],
      flag, cn);
  k_prep_all<<<257, 256, 0, stream>>>(cn, ws + KT_OFF, (__hip_bfloat16*)(ws + KNB_OFF),
                                      (__hip_bfloat16*)(ws + FHL_OFF),
                                      (__hip_bfloat16*)(ws + WMB_OFF),
                                      (float4*)(ws + XZ_OFF), (float4*)(ws + WP4_OFF),
                                      (__hip_bfloat16*)(ws + WCB_OFF));
  k_knncv<<<1536, 512, 0, stream>>>(
      (const __hip_bfloat16*)(ws + KNB_OFF), ws + KT_OFF, (const float4*)(ws + XZ_OFF),
      (const __hip_bfloat16*)(ws + FHL_OFF), (const __hip_bfloat16*)(ws + WCB_OFF),
      cn, (int*)(ws + IDX_OFF), ws + FB_OFF);
  k_mlp<<<2 * BB * (NN / 4), 256, 0, stream>>>(ws + FB_OFF, (const float4*)(ws + XZ_OFF),
                                               (const int*)(ws + IDX_OFF), (const float4*)(ws + WP4_OFF),
                                               (const __hip_bfloat16*)(ws + WMB_OFF), cn,
                                               (float*)d_out);
}

// Round 13
// 270.001 us; speedup vs baseline: 1.0713x; 1.0713x over previous
//
#include <hip/hip_runtime.h>
#include <hip/hip_bf16.h>

#define BB 2
#define NN 4096
#define CH 64

typedef __bf16 bf16x8 __attribute__((ext_vector_type(8)));
typedef float f32x4 __attribute__((ext_vector_type(4)));

__device__ __forceinline__ float lrelu(float v) { return fmaxf(v, 0.1f * v); }
__device__ __forceinline__ float tobf(const __hip_bfloat16& h) { return __bfloat162float(h); }

// canonical f32 input region offsets (element offsets within cn)
#define PC1_C 0
#define PC2_C 24576
#define F1_C 49152
#define F2_C 573440
#define K1_C 1097728
#define K2_C 1622016
#define WT11_C 2146304
#define BT11_C 2150400
#define WT22_C 2150464
#define BT22_C 2154560
#define WPOS_C 2154624
#define BPOS_C 2154816
#define WM1_C 2154880
#define BM1_C 2158976
#define WM2_C 2159040
#define BM2_C 2163136
#define CN_TOTAL 2163200

// fhl half offset (bf16 elements): fl mirror of fh
#define FHALF (2 * BB * NN * CH)

// ---- packed selection keys: (order-mapped f32 score, top 20 bits)<<12 | (4095-idx)
__device__ __forceinline__ unsigned fmap(float s) {
  unsigned u = __float_as_uint(s);
  return u ^ ((unsigned)((int)u >> 31) | 0x80000000u);
}

__device__ __forceinline__ unsigned umaxu(unsigned a, unsigned b) { return a > b ? a : b; }
__device__ __forceinline__ void casu(unsigned& a, unsigned& b) {
  unsigned mx = a > b ? a : b;
  unsigned mn = a > b ? b : a;
  a = mx; b = mn;
}

// bitonic-8 desc merge (input bitonic -> sorted desc)
__device__ __forceinline__ void bitonic8(unsigned bd[8]) {
  casu(bd[0], bd[4]); casu(bd[1], bd[5]); casu(bd[2], bd[6]); casu(bd[3], bd[7]);
  casu(bd[0], bd[2]); casu(bd[1], bd[3]); casu(bd[4], bd[6]); casu(bd[5], bd[7]);
  casu(bd[0], bd[1]); casu(bd[2], bd[3]); casu(bd[4], bd[5]); casu(bd[6], bd[7]);
}

// merge 4 new keys into sorted-desc-8 bd[] (branch-free)
__device__ __forceinline__ void merge4(unsigned bd[8], unsigned k0, unsigned k1,
                                       unsigned k2, unsigned k3) {
  casu(k0, k1); casu(k2, k3); casu(k0, k2); casu(k1, k3); casu(k1, k2);
  bd[4] = umaxu(bd[4], k3); bd[5] = umaxu(bd[5], k2);
  bd[6] = umaxu(bd[6], k1); bd[7] = umaxu(bd[7], k0);
  bitonic8(bd);
}

// top-8 of union of two sorted-desc-8 lists -> a[]
__device__ __forceinline__ void merge88(unsigned a[8], const unsigned b[8]) {
  a[0] = umaxu(a[0], b[7]); a[1] = umaxu(a[1], b[6]);
  a[2] = umaxu(a[2], b[5]); a[3] = umaxu(a[3], b[4]);
  a[4] = umaxu(a[4], b[3]); a[5] = umaxu(a[5], b[2]);
  a[6] = umaxu(a[6], b[1]); a[7] = umaxu(a[7], b[0]);
  bitonic8(a);
}

// cross-lane merge: a = top-8 of (a U partner(lane^m)'s a)
__device__ __forceinline__ void xmerge(unsigned a[8], int m) {
  unsigned t[8];
#pragma unroll
  for (int k = 0; k < 8; ++k) t[k] = (unsigned)__shfl_xor((int)a[k], m, 64);
  merge88(a, t);
}

// ---- dtype detector
__global__ void k_detect(const unsigned short* __restrict__ pc1raw, int* __restrict__ flag) {
  int lane = threadIdx.x;  // 64
  int bad = 0;
#pragma unroll
  for (int i = 0; i < 64; ++i) {
    unsigned short u = pc1raw[lane * 64 + i];
    int e = (u >> 7) & 0xFF;
    bad += (e >= 140) ? 1 : 0;  // |v| >= 2^13 or Inf/NaN
  }
#pragma unroll
  for (int s = 32; s; s >>= 1) bad += __shfl_xor(bad, s, 64);
  if (lane == 0) *flag = (bad > 16) ? 1 : 0;  // 1 = inputs are float32
}

// ---- ingest: convert all 16 inputs to canonical f32 + sanitize
__global__ __launch_bounds__(256) void k_ingest(
    const void* p0, const void* p1, const void* p2, const void* p3,
    const void* p4, const void* p5, const void* p6, const void* p7,
    const void* p8, const void* p9, const void* p10, const void* p11,
    const void* p12, const void* p13, const void* p14, const void* p15,
    const int* __restrict__ flag, float* __restrict__ dst) {
  const int cum[17] = {0, 24576, 49152, 573440, 1097728, 1622016, 2146304, 2150400,
                       2150464, 2154560, 2154624, 2154816, 2154880, 2158976, 2159040,
                       2163136, 2163200};
  size_t t = (size_t)blockIdx.x * 256 + threadIdx.x;
  if (t >= (size_t)CN_TOTAL) return;
  int seg = 0;
#pragma unroll
  for (int i = 1; i < 16; ++i) seg += (t >= (size_t)cum[i]) ? 1 : 0;
  size_t local = t - (size_t)cum[seg];
  const void* ptrs[16] = {p0, p1, p2, p3, p4, p5, p6, p7, p8, p9, p10, p11, p12, p13, p14, p15};
  const void* p = ptrs[seg];
  float v;
  if (*flag) v = ((const float*)p)[local];
  else       v = tobf(((const __hip_bfloat16*)p)[local]);
  if (!(v == v) || fabsf(v) > 1e30f) v = 0.f;  // sanitize (no-op on clean data)
  dst[t] = v;
}

// ---- fused prep (one launch, cn-based): knn-normalize, feat hi/lo, Wm->bf16,
// xyz float4, wpos, conv-W hi/lo.
__global__ __launch_bounds__(256) void k_prep_all(const float* __restrict__ cn,
                                                  float* __restrict__ knnt,
                                                  __hip_bfloat16* __restrict__ knnb,
                                                  __hip_bfloat16* __restrict__ fhl,
                                                  __hip_bfloat16* __restrict__ wmb,
                                                  float4* __restrict__ xyzt,
                                                  float4* __restrict__ wp4,
                                                  __hip_bfloat16* __restrict__ wcb) {
  int bid = blockIdx.x;
  if (bid < 64) {
    int t = bid * 256 + threadIdx.x;  // 2*BB*NN
    int n = t & (NN - 1);
    int b = (t >> 12) & 1;
    int a = t >> 13;
    const float* col = cn + (a ? K2_C : K1_C) + (size_t)b * CH * NN + n;
    float s = 0.f;
#pragma unroll
    for (int c = 0; c < CH; ++c) { float v = col[(size_t)c * NN]; s += v * v; }
    float inv = 1.0f / sqrtf(s + 1e-8f);
    size_t row = (size_t)(a * BB + b) * NN + n;
    float* o = knnt + row * CH;
    __hip_bfloat16* ob = knnb + row * CH;
#pragma unroll
    for (int c = 0; c < CH; ++c) {
      float v = col[(size_t)c * NN] * inv;
      o[c] = v;
      ob[c] = __float2bfloat16(v);
    }
  } else if (bid < 128) {
    int t = (bid - 64) * 256 + threadIdx.x;  // 2*BB*NN
    int n = t & (NN - 1);
    int b = (t >> 12) & 1;
    int a = t >> 13;
    const float* col = cn + (a ? F2_C : F1_C) + (size_t)b * CH * NN + n;
    __hip_bfloat16* oh = fhl + ((size_t)(a * BB + b) * NN + n) * CH;
    __hip_bfloat16* ol = oh + FHALF;
#pragma unroll
    for (int c = 0; c < CH; ++c) {
      float v = col[(size_t)c * NN];
      __hip_bfloat16 hi = __float2bfloat16(v);
      oh[c] = hi;
      ol[c] = __float2bfloat16(v - tobf(hi));
    }
  } else if (bid < 160) {
    int t = (bid - 128) * 256 + threadIdx.x;  // 8192
    float v = (t < 4096) ? cn[WM1_C + t] : cn[WM2_C + (t - 4096)];
    wmb[t] = __float2bfloat16(v);
  } else if (bid < 224) {
    int t = (bid - 160) * 256 + threadIdx.x;  // 2*BB*NN
    int n = t & (NN - 1);
    int b = (t >> 12) & 1;
    int a = t >> 13;
    const float* p = cn + (a ? PC2_C : PC1_C) + (size_t)b * 3 * NN + n;
    float x = p[0], y = p[NN], z = p[2 * NN];
    xyzt[(size_t)(a * BB + b) * NN + n] = make_float4(x, y, z, x * x + y * y + z * z);
  } else if (bid == 224) {
    int c = threadIdx.x;
    if (c < 64)
      wp4[c] = make_float4(cn[WPOS_C + 3 * c], cn[WPOS_C + 3 * c + 1],
                           cn[WPOS_C + 3 * c + 2], cn[BPOS_C + c]);
  } else {
    // conv weight hi/lo split: wcb[w][d*64+c] hi at [0,8192), lo at [8192,16384)
    int t = (bid - 225) * 256 + threadIdx.x;  // 8192 = 2 W x 4096
    int w = t >> 12, e = t & 4095;
    float v = cn[(w ? WT22_C : WT11_C) + e];
    __hip_bfloat16 hi = __float2bfloat16(v);
    __hip_bfloat16 lo = __float2bfloat16(v - tobf(hi));
    wcb[w * 4096 + e] = hi;
    wcb[8192 + w * 4096 + e] = lo;
  }
}

// ======================================================================
// R17 k_knncv (resubmit; R12 run was an infra failure, no counters):
// R16's parallel single-barrier extraction KEPT, __launch_bounds__ restored
// to (512,4). R16 lesson (w=6): VGPR 52->40 with 16MB scratch spill, dur
// 126->141-157. R12 lesson (w=8): hard spill. The scan needs ~52 live regs;
// (512,4)'s 128-budget is the only safe cap. Extraction: dump BOTH key
// sets, ONE barrier, waves 0-3 cosine / 4-7 euclid, 4 queries/wave in
// 16-lane groups, bitonic-16 final sort.
// ======================================================================
__global__ __launch_bounds__(512, 4) void k_knncv(const __hip_bfloat16* __restrict__ knnb,
                                                  const float* __restrict__ knnt,
                                                  const float4* __restrict__ xyzt,
                                                  const __hip_bfloat16* __restrict__ fhl,
                                                  const __hip_bfloat16* __restrict__ wcb,
                                                  const float* __restrict__ cn,
                                                  int* __restrict__ idxf,
                                                  float* __restrict__ fbuf) {
  int bid = blockIdx.x;
  if (bid >= 1024) {
    // ---------------- conv path (no barriers, early return) ----------------
    int cb = bid - 1024;  // 512: b(1) | a(1) | pair(7 high); ntile = pair*2 + (tid>>8)
    int b = cb & 1;
    int a = (cb >> 1) & 1;
    int ntile = (cb >> 2) * 2 + (threadIdx.x >> 8);
    int t = threadIdx.x & 255;
    int dt = t >> 6;
    int lane = t & 63;
    int lo = lane & 15, g = lane >> 4;

    const __hip_bfloat16* fb = fhl + ((size_t)(a * BB + b) * NN + ntile * 16 + lo) * CH;
    bf16x8 ah0 = *reinterpret_cast<const bf16x8*>(fb + g * 8);
    bf16x8 ah1 = *reinterpret_cast<const bf16x8*>(fb + 32 + g * 8);
    bf16x8 al0 = *reinterpret_cast<const bf16x8*>(fb + FHALF + g * 8);
    bf16x8 al1 = *reinterpret_cast<const bf16x8*>(fb + FHALF + 32 + g * 8);

#pragma unroll
    for (int w = 0; w < 2; ++w) {
      const __hip_bfloat16* wb = wcb + w * 4096 + (dt * 16 + lo) * 64;
      bf16x8 wh0 = *reinterpret_cast<const bf16x8*>(wb + g * 8);
      bf16x8 wh1 = *reinterpret_cast<const bf16x8*>(wb + 32 + g * 8);
      bf16x8 wl0 = *reinterpret_cast<const bf16x8*>(wb + 8192 + g * 8);
      bf16x8 wl1 = *reinterpret_cast<const bf16x8*>(wb + 8192 + 32 + g * 8);
      float bv = cn[(w ? BT22_C : BT11_C) + dt * 16 + lo];
      f32x4 acc = {bv, bv, bv, bv};
      acc = __builtin_amdgcn_mfma_f32_16x16x32_bf16(ah0, wh0, acc, 0, 0, 0);
      acc = __builtin_amdgcn_mfma_f32_16x16x32_bf16(ah1, wh1, acc, 0, 0, 0);
      acc = __builtin_amdgcn_mfma_f32_16x16x32_bf16(al0, wh0, acc, 0, 0, 0);
      acc = __builtin_amdgcn_mfma_f32_16x16x32_bf16(al1, wh1, acc, 0, 0, 0);
      acc = __builtin_amdgcn_mfma_f32_16x16x32_bf16(ah0, wl0, acc, 0, 0, 0);
      acc = __builtin_amdgcn_mfma_f32_16x16x32_bf16(ah1, wl1, acc, 0, 0, 0);
      int sel = a ? (w ? 1 : 2) : (w ? 3 : 0);
      float* ob = fbuf + ((size_t)(sel * BB + b) * NN + ntile * 16 + g * 4) * CH + dt * 16 + lo;
      ob[0 * CH] = acc[0];
      ob[1 * CH] = acc[1];
      ob[2 * CH] = acc[2];
      ob[3 * CH] = acc[3];
    }
    return;
  }

  // ---------------- knn path ----------------
  __shared__ unsigned skc[16 * 8 * 9];  // cosine keys, 4.6 KB
  __shared__ unsigned ske[16 * 8 * 9];  // euclid keys, 4.6 KB
  __shared__ int cidx[2 * 16 * 16];     // [phase][query][16 cand]
  int b = bid & 1;
  int x = (bid >> 1) & 1;
  int qt = bid >> 2;
  int w = threadIdx.x >> 6;
  int lane = threadIdx.x & 63;
  int lo = lane & 15, g = lane >> 4;
  int q0 = qt * 16;
  int j0 = w * (NN / 8);
  size_t qbase = (size_t)(x * BB + b) * NN;
  size_t dbase = (size_t)((1 - x) * BB + b) * NN;

  const __hip_bfloat16* qb = knnb + (qbase + q0) * CH;
  bf16x8 qf0 = *reinterpret_cast<const bf16x8*>(qb + lo * CH + g * 8);
  bf16x8 qf1 = *reinterpret_cast<const bf16x8*>(qb + lo * CH + 32 + g * 8);
  const __hip_bfloat16* db = knnb + dbase * CH;
  const float4 q4 = xyzt[qbase + q0 + lo];
  const float4* dbx = xyzt + dbase;
  float tx = 2.f * q4.x, ty = 2.f * q4.y, tz = 2.f * q4.z;

  unsigned bc0[8], bc1[8], be0[8], be1[8];
#pragma unroll
  for (int k = 0; k < 8; ++k) { bc0[k] = 0u; bc1[k] = 0u; be0[k] = 0u; be1[k] = 0u; }

  auto STEP = [&](const bf16x8& A0, const bf16x8& A1, const float4& P0,
                  const float4& P1, const float4& P2, const float4& P3,
                  int rcv, unsigned (&bc)[8], unsigned (&be)[8]) {
    f32x4 acc = {0.f, 0.f, 0.f, 0.f};
    acc = __builtin_amdgcn_mfma_f32_16x16x32_bf16(A0, qf0, acc, 0, 0, 0);
    acc = __builtin_amdgcn_mfma_f32_16x16x32_bf16(A1, qf1, acc, 0, 0, 0);
    float v0 = fmaf(tx, P0.x, fmaf(ty, P0.y, fmaf(tz, P0.z, -P0.w)));
    float v1 = fmaf(tx, P1.x, fmaf(ty, P1.y, fmaf(tz, P1.z, -P1.w)));
    float v2 = fmaf(tx, P2.x, fmaf(ty, P2.y, fmaf(tz, P2.z, -P2.w)));
    float v3 = fmaf(tx, P3.x, fmaf(ty, P3.y, fmaf(tz, P3.z, -P3.w)));
    unsigned r = (unsigned)rcv;
    merge4(bc, (__float_as_uint(acc[0] + 4.0f) & 0xFFFFF000u) | r,
               (__float_as_uint(acc[1] + 4.0f) & 0xFFFFF000u) | (r - 1),
               (__float_as_uint(acc[2] + 4.0f) & 0xFFFFF000u) | (r - 2),
               (__float_as_uint(acc[3] + 4.0f) & 0xFFFFF000u) | (r - 3));
    merge4(be, (fmap(v0) & 0xFFFFF000u) | r,
               (fmap(v1) & 0xFFFFF000u) | (r - 1),
               (fmap(v2) & 0xFFFFF000u) | (r - 2),
               (fmap(v3) & 0xFFFFF000u) | (r - 3));
  };

  // ---- pipelined scan: 32 tiles, A=even / B=odd, one-tile prefetch ahead
  const __hip_bfloat16* arA = db + (size_t)(j0 + lo) * CH + g * 8;
  const __hip_bfloat16* arB = arA + 16 * CH;
  const float4* peA = dbx + j0 + g * 4;
  const float4* peB = peA + 16;
  int rc = 4095 - j0 - g * 4;

  bf16x8 aA0 = *reinterpret_cast<const bf16x8*>(arA);
  bf16x8 aA1 = *reinterpret_cast<const bf16x8*>(arA + 32);
  float4 pA0 = peA[0], pA1 = peA[1], pA2 = peA[2], pA3 = peA[3];

  for (int i = 0; i < 15; ++i) {
    bf16x8 aB0 = *reinterpret_cast<const bf16x8*>(arB);
    bf16x8 aB1 = *reinterpret_cast<const bf16x8*>(arB + 32);
    float4 pB0 = peB[0], pB1 = peB[1], pB2 = peB[2], pB3 = peB[3];
    STEP(aA0, aA1, pA0, pA1, pA2, pA3, rc, bc0, be0);
    arA += 32 * CH; peA += 32;
    aA0 = *reinterpret_cast<const bf16x8*>(arA);
    aA1 = *reinterpret_cast<const bf16x8*>(arA + 32);
    pA0 = peA[0]; pA1 = peA[1]; pA2 = peA[2]; pA3 = peA[3];
    STEP(aB0, aB1, pB0, pB1, pB2, pB3, rc - 16, bc1, be1);
    arB += 32 * CH; peB += 32;
    rc -= 32;
  }
  {
    bf16x8 aB0 = *reinterpret_cast<const bf16x8*>(arB);
    bf16x8 aB1 = *reinterpret_cast<const bf16x8*>(arB + 32);
    float4 pB0 = peB[0], pB1 = peB[1], pB2 = peB[2], pB3 = peB[3];
    STEP(aA0, aA1, pA0, pA1, pA2, pA3, rc, bc0, be0);
    STEP(aB0, aB1, pB0, pB1, pB2, pB3, rc - 16, bc1, be1);
  }
  merge88(bc0, bc1);
  merge88(be0, be1);
  // cross-group register merge: 32 substreams -> 8 (one per wave, per query)
  xmerge(bc0, 16); xmerge(bc0, 32);
  xmerge(be0, 16); xmerge(be0, 32);

  // ---- dump BOTH phases' keys, one barrier
  if (g == 0) {
#pragma unroll
    for (int k = 0; k < 8; ++k) {
      skc[(lo * 8 + k) * 9 + w] = bc0[k];
      ske[(lo * 8 + k) * 9 + w] = be0[k];
    }
  }
  __syncthreads();

  // ---- unified extraction: waves 0-3 cosine, 4-7 euclid; 4 queries/wave,
  //      16-lane groups (8 slots duplicated x2 within group)
  {
    int p = w >> 2;                          // 0 = cosine, 1 = euclid
    int qq = (w & 3) * 4 + (lane >> 4);      // this group's query (0..15)
    int sl = lane & 15;
    const unsigned* skp = p ? ske : skc;
    unsigned e[16];
#pragma unroll
    for (int k = 0; k < 8; ++k) e[k] = skp[(qq * 8 + k) * 9 + (sl & 7)];
#pragma unroll
    for (int k = 8; k < 16; ++k) e[k] = 0u;
#pragma unroll
    for (int s = 1; s < 8; s <<= 1) {
      unsigned f[16];
#pragma unroll
      for (int k = 0; k < 16; ++k) f[k] = (unsigned)__shfl_xor((int)e[k], s, 64);
#pragma unroll
      for (int i = 0; i < 16; ++i) e[i] = umaxu(e[i], f[15 - i]);
      casu(e[0], e[8]); casu(e[1], e[9]); casu(e[2], e[10]); casu(e[3], e[11]);
      casu(e[4], e[12]); casu(e[5], e[13]); casu(e[6], e[14]); casu(e[7], e[15]);
      casu(e[0], e[4]); casu(e[1], e[5]); casu(e[2], e[6]); casu(e[3], e[7]);
      casu(e[8], e[12]); casu(e[9], e[13]); casu(e[10], e[14]); casu(e[11], e[15]);
      casu(e[0], e[2]); casu(e[1], e[3]); casu(e[4], e[6]); casu(e[5], e[7]);
      casu(e[8], e[10]); casu(e[9], e[11]); casu(e[12], e[14]); casu(e[13], e[15]);
      casu(e[0], e[1]); casu(e[2], e[3]); casu(e[4], e[5]); casu(e[6], e[7]);
      casu(e[8], e[9]); casu(e[10], e[11]); casu(e[12], e[13]); casu(e[14], e[15]);
    }
    if (sl == 0) {
#pragma unroll
      for (int k = 0; k < 16; ++k) cidx[(p * 16 + qq) * 16 + k] = 4095 - (int)(e[k] & 4095u);
    }
    int idx = cidx[(p * 16 + qq) * 16 + sl];  // same-wave lockstep write->read
    float v;
    if (p == 0) {
      // cosine: exact f32 dot of normalized rows (one lane per candidate)
      const float4* qr = reinterpret_cast<const float4*>(knnt + (qbase + q0 + qq) * CH);
      const float4* dr = reinterpret_cast<const float4*>(knnt + (dbase + idx) * CH);
      v = 0.f;
#pragma unroll 4
      for (int cb = 0; cb < 16; ++cb) {
        float4 qv = qr[cb], dv = dr[cb];
        v += qv.x * dv.x + qv.y * dv.y + qv.z * dv.z + qv.w * dv.w;
      }
    } else {
      // euclid: exact f32 key = 2*q.p - |p|^2
      const float4 qx4 = xyzt[qbase + q0 + qq];
      float4 pp = xyzt[dbase + idx];
      v = fmaf(2.f * qx4.x, pp.x, fmaf(2.f * qx4.y, pp.y, fmaf(2.f * qx4.z, pp.z, -pp.w)));
    }
    // bitonic sort 16 distinct candidates desc by (v, idx asc); take first 8
    int ii = idx;
#pragma unroll
    for (int k = 2; k <= 16; k <<= 1) {
#pragma unroll
      for (int j = k >> 1; j >= 1; j >>= 1) {
        float ov = __shfl_xor(v, j, 64);
        int oi = __shfl_xor(ii, j, 64);
        bool ob = (ov > v) || (ov == v && oi < ii);
        bool want = (((sl & k) == 0) == ((sl & j) == 0));
        bool take = (want == ob);
        v = take ? ov : v;
        ii = take ? oi : ii;
      }
    }
    if (sl < 8) idxf[(qbase + q0 + qq) * 16 + p * 8 + sl] = ii;
  }
}

// ---- fused gather + pos-conv + 2x MFMA MLP + neighbor max. One wave per query.
// XCD-aware decode (x,b in low bid bits).
__global__ __launch_bounds__(256) void k_mlp(const float* __restrict__ fbuf,
                                             const float4* __restrict__ xyzt,
                                             const int* __restrict__ idxf,
                                             const float4* __restrict__ wp4,
                                             const __hip_bfloat16* __restrict__ wmb,
                                             const float* __restrict__ cn,
                                             float* __restrict__ out) {
  __shared__ __bf16 h1s[4 * 16 * 72];  // per-wave 16 rows x stride 72
  const int t = threadIdx.x;
  const int wv = t >> 6, L = t & 63;
  const int lo = L & 15, g = L >> 4;
  int bid = blockIdx.x;  // 4096: b(1) | x(1) | qt(10 high)
  const int b = bid & 1;
  const int x = (bid >> 1) & 1;
  const int qt = bid >> 2;
  const int q = qt * 4 + wv;

  bf16x8 w1f[4][2], w2f[4][2];
#pragma unroll
  for (int tt = 0; tt < 4; ++tt)
#pragma unroll
    for (int kc = 0; kc < 2; ++kc) {
      int e = tt * 16 + lo, c0 = kc * 32 + g * 8;
      w1f[tt][kc] = *reinterpret_cast<const bf16x8*>(wmb + e * 64 + c0);
      w2f[tt][kc] = *reinterpret_cast<const bf16x8*>(wmb + 4096 + e * 64 + c0);
    }

  const float* pq  = fbuf + ((size_t)((x ? 2 : 0) * BB + b)) * NN * CH;
  const float* pdb = fbuf + ((size_t)((x ? 3 : 1) * BB + b)) * NN * CH;
  const float4* qx  = xyzt + (size_t)(x * BB + b) * NN;
  const float4* dbx = xyzt + (size_t)((1 - x) * BB + b) * NN;

  const int m = lo;
  int jm = idxf[(((size_t)x * BB + b) * NN + q) * 16 + m];
  jm &= (NN - 1);
  const float4 q4 = qx[q];
  const float4 p4 = dbx[jm];
  const float dx = p4.x - q4.x, dy = p4.y - q4.y, dz = p4.z - q4.z;

  const float4* g2v = reinterpret_cast<const float4*>(pdb + (size_t)jm * CH);
  const float4* pqv = reinterpret_cast<const float4*>(pq + (size_t)q * CH);
  float hv[16];
  {
    float4 t0 = g2v[g * 2], t1 = g2v[g * 2 + 1], t2 = g2v[g * 2 + 8], t3 = g2v[g * 2 + 9];
    float4 u0 = pqv[g * 2], u1 = pqv[g * 2 + 1], u2 = pqv[g * 2 + 8], u3 = pqv[g * 2 + 9];
    hv[0] = t0.x + u0.x; hv[1] = t0.y + u0.y; hv[2] = t0.z + u0.z; hv[3] = t0.w + u0.w;
    hv[4] = t1.x + u1.x; hv[5] = t1.y + u1.y; hv[6] = t1.z + u1.z; hv[7] = t1.w + u1.w;
    hv[8] = t2.x + u2.x; hv[9] = t2.y + u2.y; hv[10] = t2.z + u2.z; hv[11] = t2.w + u2.w;
    hv[12] = t3.x + u3.x; hv[13] = t3.y + u3.y; hv[14] = t3.z + u3.z; hv[15] = t3.w + u3.w;
  }

  bf16x8 a0, a1;
#pragma unroll
  for (int kc = 0; kc < 2; ++kc) {
#pragma unroll
    for (int j = 0; j < 8; ++j) {
      int c = kc * 32 + g * 8 + j;
      float4 wp = wp4[c];
      float v = hv[kc * 8 + j] + wp.x * dx + wp.y * dy + wp.z * dz + wp.w;
      v = lrelu(v);
      if (kc == 0) a0[j] = (__bf16)v; else a1[j] = (__bf16)v;
    }
  }

  __bf16* hrow = h1s + wv * 16 * 72;
#pragma unroll
  for (int tt = 0; tt < 4; ++tt) {
    float bv = cn[BM1_C + tt * 16 + lo];
    f32x4 acc = {bv, bv, bv, bv};
    acc = __builtin_amdgcn_mfma_f32_16x16x32_bf16(a0, w1f[tt][0], acc, 0, 0, 0);
    acc = __builtin_amdgcn_mfma_f32_16x16x32_bf16(a1, w1f[tt][1], acc, 0, 0, 0);
#pragma unroll
    for (int r = 0; r < 4; ++r) {
      float v = lrelu(acc[r]);
      hrow[(g * 4 + r) * 72 + tt * 16 + lo] = (__bf16)v;
    }
  }
  __syncthreads();
  bf16x8 h1a = *reinterpret_cast<const bf16x8*>(hrow + m * 72 + g * 8);
  bf16x8 h1b = *reinterpret_cast<const bf16x8*>(hrow + m * 72 + 32 + g * 8);

  size_t obase = ((size_t)(x * BB + b) * CH) * NN;
#pragma unroll
  for (int tt = 0; tt < 4; ++tt) {
    float bv = cn[BM2_C + tt * 16 + lo];
    f32x4 acc = {bv, bv, bv, bv};
    acc = __builtin_amdgcn_mfma_f32_16x16x32_bf16(h1a, w2f[tt][0], acc, 0, 0, 0);
    acc = __builtin_amdgcn_mfma_f32_16x16x32_bf16(h1b, w2f[tt][1], acc, 0, 0, 0);
    float v = fmaxf(fmaxf(lrelu(acc[0]), lrelu(acc[1])), fmaxf(lrelu(acc[2]), lrelu(acc[3])));
    v = fmaxf(v, __shfl_xor(v, 16, 64));
    v = fmaxf(v, __shfl_xor(v, 32, 64));
    if (g == 0) out[obase + (size_t)(tt * 16 + lo) * NN + q] = v;
  }
}

// workspace layout (float units)
#define CN_OFF 0
#define FB_OFF ((size_t)CN_TOTAL)
#define KT_OFF (FB_OFF + (size_t)4 * BB * NN * CH)
#define XZ_OFF (KT_OFF + (size_t)2 * BB * NN * CH)
#define WP4_OFF (XZ_OFF + (size_t)2 * BB * NN * 4)
#define WMB_OFF (WP4_OFF + 256)
#define IDX_OFF (WMB_OFF + 4096)
#define FLAG_OFF (IDX_OFF + 262144)
#define KNB_OFF (FLAG_OFF + 4)
#define FHL_OFF (KNB_OFF + (size_t)BB * NN * CH)
#define WCB_OFF (FHL_OFF + (size_t)2 * BB * NN * CH)

extern "C" void kernel_launch(void* const* d_in, const int* in_sizes, int n_in,
                              void* d_out, int out_size, void* d_ws, size_t ws_size,
                              hipStream_t stream) {
  float* ws = (float*)d_ws;
  float* cn = ws + CN_OFF;
  int* flag = (int*)(ws + FLAG_OFF);

  k_detect<<<1, 64, 0, stream>>>((const unsigned short*)d_in[0], flag);
  k_ingest<<<(CN_TOTAL + 255) / 256, 256, 0, stream>>>(
      d_in[0], d_in[1], d_in[2], d_in[3], d_in[4], d_in[5], d_in[6], d_in[7],
      d_in[8], d_in[9], d_in[10], d_in[11], d_in[12], d_in[13], d_in[14], d_in[15],
      flag, cn);
  k_prep_all<<<257, 256, 0, stream>>>(cn, ws + KT_OFF, (__hip_bfloat16*)(ws + KNB_OFF),
                                      (__hip_bfloat16*)(ws + FHL_OFF),
                                      (__hip_bfloat16*)(ws + WMB_OFF),
                                      (float4*)(ws + XZ_OFF), (float4*)(ws + WP4_OFF),
                                      (__hip_bfloat16*)(ws + WCB_OFF));
  k_knncv<<<1536, 512, 0, stream>>>(
      (const __hip_bfloat16*)(ws + KNB_OFF), ws + KT_OFF, (const float4*)(ws + XZ_OFF),
      (const __hip_bfloat16*)(ws + FHL_OFF), (const __hip_bfloat16*)(ws + WCB_OFF),
      cn, (int*)(ws + IDX_OFF), ws + FB_OFF);
  k_mlp<<<2 * BB * (NN / 4), 256, 0, stream>>>(ws + FB_OFF, (const float4*)(ws + XZ_OFF),
                                               (const int*)(ws + IDX_OFF), (const float4*)(ws + WP4_OFF),
                                               (const __hip_bfloat16*)(ws + WMB_OFF), cn,
                                               (float*)d_out);
}

// Round 14
// 263.179 us; speedup vs baseline: 1.0991x; 1.0259x over previous
//
#include <hip/hip_runtime.h>
#include <hip/hip_bf16.h>

#define BB 2
#define NN 4096
#define CH 64

typedef __bf16 bf16x8 __attribute__((ext_vector_type(8)));
typedef float f32x4 __attribute__((ext_vector_type(4)));

__device__ __forceinline__ float lrelu(float v) { return fmaxf(v, 0.1f * v); }
__device__ __forceinline__ float tobf(const __hip_bfloat16& h) { return __bfloat162float(h); }

// canonical f32 input region offsets (element offsets within cn)
#define PC1_C 0
#define PC2_C 24576
#define F1_C 49152
#define F2_C 573440
#define K1_C 1097728
#define K2_C 1622016
#define WT11_C 2146304
#define BT11_C 2150400
#define WT22_C 2150464
#define BT22_C 2154560
#define WPOS_C 2154624
#define BPOS_C 2154816
#define WM1_C 2154880
#define BM1_C 2158976
#define WM2_C 2159040
#define BM2_C 2163136
#define CN_TOTAL 2163200

// fhl half offset (bf16 elements): fl mirror of fh
#define FHALF (2 * BB * NN * CH)

// ---- packed selection keys: (order-mapped f32 score, top 20 bits)<<12 | (4095-idx)
__device__ __forceinline__ unsigned fmap(float s) {
  unsigned u = __float_as_uint(s);
  return u ^ ((unsigned)((int)u >> 31) | 0x80000000u);
}

__device__ __forceinline__ unsigned umaxu(unsigned a, unsigned b) { return a > b ? a : b; }
__device__ __forceinline__ void casu(unsigned& a, unsigned& b) {
  unsigned mx = a > b ? a : b;
  unsigned mn = a > b ? b : a;
  a = mx; b = mn;
}

// bitonic-8 desc merge (input bitonic -> sorted desc)
__device__ __forceinline__ void bitonic8(unsigned bd[8]) {
  casu(bd[0], bd[4]); casu(bd[1], bd[5]); casu(bd[2], bd[6]); casu(bd[3], bd[7]);
  casu(bd[0], bd[2]); casu(bd[1], bd[3]); casu(bd[4], bd[6]); casu(bd[5], bd[7]);
  casu(bd[0], bd[1]); casu(bd[2], bd[3]); casu(bd[4], bd[5]); casu(bd[6], bd[7]);
}

// merge 4 new keys into sorted-desc-8 bd[] (branch-free)
__device__ __forceinline__ void merge4(unsigned bd[8], unsigned k0, unsigned k1,
                                       unsigned k2, unsigned k3) {
  casu(k0, k1); casu(k2, k3); casu(k0, k2); casu(k1, k3); casu(k1, k2);
  bd[4] = umaxu(bd[4], k3); bd[5] = umaxu(bd[5], k2);
  bd[6] = umaxu(bd[6], k1); bd[7] = umaxu(bd[7], k0);
  bitonic8(bd);
}

// top-8 of union of two sorted-desc-8 lists -> a[]
__device__ __forceinline__ void merge88(unsigned a[8], const unsigned b[8]) {
  a[0] = umaxu(a[0], b[7]); a[1] = umaxu(a[1], b[6]);
  a[2] = umaxu(a[2], b[5]); a[3] = umaxu(a[3], b[4]);
  a[4] = umaxu(a[4], b[3]); a[5] = umaxu(a[5], b[2]);
  a[6] = umaxu(a[6], b[1]); a[7] = umaxu(a[7], b[0]);
  bitonic8(a);
}

// cross-lane merge: a = top-8 of (a U partner(lane^m)'s a)
__device__ __forceinline__ void xmerge(unsigned a[8], int m) {
  unsigned t[8];
#pragma unroll
  for (int k = 0; k < 8; ++k) t[k] = (unsigned)__shfl_xor((int)a[k], m, 64);
  merge88(a, t);
}

// ---- per-wave dtype detect (reads pc1's first 8KB; L2-hot after first block)
__device__ __forceinline__ bool detect_f32(const unsigned short* __restrict__ pc1raw) {
  int lane = threadIdx.x & 63;
  const uint4* p4 = reinterpret_cast<const uint4*>(pc1raw);
  int bad = 0;
#pragma unroll
  for (int k = 0; k < 8; ++k) {
    uint4 v = p4[lane * 8 + k];
    bad += (((v.x >> 7) & 0xFF) >= 140) + (((v.x >> 23) & 0xFF) >= 140);
    bad += (((v.y >> 7) & 0xFF) >= 140) + (((v.y >> 23) & 0xFF) >= 140);
    bad += (((v.z >> 7) & 0xFF) >= 140) + (((v.z >> 23) & 0xFF) >= 140);
    bad += (((v.w >> 7) & 0xFF) >= 140) + (((v.w >> 23) & 0xFF) >= 140);
  }
#pragma unroll
  for (int s = 32; s; s >>= 1) bad += __shfl_xor(bad, s, 64);
  return bad > 16;  // true = inputs are float32
}

__device__ __forceinline__ float sani(float v) {
  if (!(v == v) || fabsf(v) > 1e30f) v = 0.f;
  return v;
}

// ---- ingest R18: detect fused (wave 0 + LDS broadcast), 4-wide vectorized.
// All segment starts are divisible by 64 -> in-segment path is 16B/8B aligned.
__global__ __launch_bounds__(256) void k_ingest2(
    const void* p0, const void* p1, const void* p2, const void* p3,
    const void* p4, const void* p5, const void* p6, const void* p7,
    const void* p8, const void* p9, const void* p10, const void* p11,
    const void* p12, const void* p13, const void* p14, const void* p15,
    float* __restrict__ dst) {
  __shared__ int sflag;
  if (threadIdx.x < 64) {
    bool f = detect_f32((const unsigned short*)p0);
    if (threadIdx.x == 0) sflag = f ? 1 : 0;
  }
  __syncthreads();
  bool f32 = sflag != 0;

  const int cum[17] = {0, 24576, 49152, 573440, 1097728, 1622016, 2146304, 2150400,
                       2150464, 2154560, 2154624, 2154816, 2154880, 2158976, 2159040,
                       2163136, 2163200};
  const void* ptrs[16] = {p0, p1, p2, p3, p4, p5, p6, p7, p8, p9, p10, p11, p12, p13, p14, p15};
  size_t t4 = ((size_t)blockIdx.x * 256 + threadIdx.x) * 4;
  if (t4 >= (size_t)CN_TOTAL) return;
  int seg = 0, seg3 = 0;
  size_t t4e = t4 + 3;
#pragma unroll
  for (int i = 1; i < 16; ++i) {
    seg += (t4 >= (size_t)cum[i]) ? 1 : 0;
    seg3 += (t4e >= (size_t)cum[i]) ? 1 : 0;
  }
  if (seg == seg3 && t4e < (size_t)CN_TOTAL) {
    const void* p = ptrs[seg];
    size_t local = t4 - (size_t)cum[seg];
    float4 v;
    if (f32) {
      v = *reinterpret_cast<const float4*>((const float*)p + local);
    } else {
      ushort4 u = *reinterpret_cast<const ushort4*>((const unsigned short*)p + local);
      v.x = __uint_as_float((unsigned)u.x << 16);
      v.y = __uint_as_float((unsigned)u.y << 16);
      v.z = __uint_as_float((unsigned)u.z << 16);
      v.w = __uint_as_float((unsigned)u.w << 16);
    }
    v.x = sani(v.x); v.y = sani(v.y); v.z = sani(v.z); v.w = sani(v.w);
    *reinterpret_cast<float4*>(dst + t4) = v;
  } else {
#pragma unroll
    for (int i = 0; i < 4; ++i) {
      size_t t = t4 + i;
      if (t >= (size_t)CN_TOTAL) break;
      int s = 0;
#pragma unroll
      for (int k = 1; k < 16; ++k) s += (t >= (size_t)cum[k]) ? 1 : 0;
      const void* p = ptrs[s];
      size_t local = t - (size_t)cum[s];
      float v = f32 ? ((const float*)p)[local]
                    : __uint_as_float((unsigned)((const unsigned short*)p)[local] << 16);
      dst[t] = sani(v);
    }
  }
}

// ---- fused prep (one launch, cn-based): knn-normalize (single-pass, regs),
// feat hi/lo, Wm->bf16, xyz float4, wpos, conv-W hi/lo.
__global__ __launch_bounds__(256) void k_prep_all(const float* __restrict__ cn,
                                                  float* __restrict__ knnt,
                                                  __hip_bfloat16* __restrict__ knnb,
                                                  __hip_bfloat16* __restrict__ fhl,
                                                  __hip_bfloat16* __restrict__ wmb,
                                                  float4* __restrict__ xyzt,
                                                  float4* __restrict__ wp4,
                                                  __hip_bfloat16* __restrict__ wcb) {
  int bid = blockIdx.x;
  if (bid < 64) {
    int t = bid * 256 + threadIdx.x;  // 2*BB*NN
    int n = t & (NN - 1);
    int b = (t >> 12) & 1;
    int a = t >> 13;
    const float* col = cn + (a ? K2_C : K1_C) + (size_t)b * CH * NN + n;
    float vals[CH];  // fully unrolled -> static indices, stays in VGPRs
    float s = 0.f;
#pragma unroll
    for (int c = 0; c < CH; ++c) {
      float v = col[(size_t)c * NN];
      vals[c] = v;
      s += v * v;
    }
    float inv = 1.0f / sqrtf(s + 1e-8f);
    size_t row = (size_t)(a * BB + b) * NN + n;
    float* o = knnt + row * CH;
    __hip_bfloat16* ob = knnb + row * CH;
#pragma unroll
    for (int c = 0; c < CH; ++c) {
      float v = vals[c] * inv;
      o[c] = v;
      ob[c] = __float2bfloat16(v);
    }
  } else if (bid < 128) {
    int t = (bid - 64) * 256 + threadIdx.x;  // 2*BB*NN
    int n = t & (NN - 1);
    int b = (t >> 12) & 1;
    int a = t >> 13;
    const float* col = cn + (a ? F2_C : F1_C) + (size_t)b * CH * NN + n;
    __hip_bfloat16* oh = fhl + ((size_t)(a * BB + b) * NN + n) * CH;
    __hip_bfloat16* ol = oh + FHALF;
#pragma unroll
    for (int c = 0; c < CH; ++c) {
      float v = col[(size_t)c * NN];
      __hip_bfloat16 hi = __float2bfloat16(v);
      oh[c] = hi;
      ol[c] = __float2bfloat16(v - tobf(hi));
    }
  } else if (bid < 160) {
    int t = (bid - 128) * 256 + threadIdx.x;  // 8192
    float v = (t < 4096) ? cn[WM1_C + t] : cn[WM2_C + (t - 4096)];
    wmb[t] = __float2bfloat16(v);
  } else if (bid < 224) {
    int t = (bid - 160) * 256 + threadIdx.x;  // 2*BB*NN
    int n = t & (NN - 1);
    int b = (t >> 12) & 1;
    int a = t >> 13;
    const float* p = cn + (a ? PC2_C : PC1_C) + (size_t)b * 3 * NN + n;
    float x = p[0], y = p[NN], z = p[2 * NN];
    xyzt[(size_t)(a * BB + b) * NN + n] = make_float4(x, y, z, x * x + y * y + z * z);
  } else if (bid == 224) {
    int c = threadIdx.x;
    if (c < 64)
      wp4[c] = make_float4(cn[WPOS_C + 3 * c], cn[WPOS_C + 3 * c + 1],
                           cn[WPOS_C + 3 * c + 2], cn[BPOS_C + c]);
  } else {
    // conv weight hi/lo split: wcb[w][d*64+c] hi at [0,8192), lo at [8192,16384)
    int t = (bid - 225) * 256 + threadIdx.x;  // 8192 = 2 W x 4096
    int w = t >> 12, e = t & 4095;
    float v = cn[(w ? WT22_C : WT11_C) + e];
    __hip_bfloat16 hi = __float2bfloat16(v);
    __hip_bfloat16 lo = __float2bfloat16(v - tobf(hi));
    wcb[w * 4096 + e] = hi;
    wcb[8192 + w * 4096 + e] = lo;
  }
}

// ======================================================================
// k_knncv (unchanged from R17, 119.5us verified): knn scan + parallel
// single-barrier extraction at (512,4); conv fused as bids 1024..1535.
// ======================================================================
__global__ __launch_bounds__(512, 4) void k_knncv(const __hip_bfloat16* __restrict__ knnb,
                                                  const float* __restrict__ knnt,
                                                  const float4* __restrict__ xyzt,
                                                  const __hip_bfloat16* __restrict__ fhl,
                                                  const __hip_bfloat16* __restrict__ wcb,
                                                  const float* __restrict__ cn,
                                                  int* __restrict__ idxf,
                                                  float* __restrict__ fbuf) {
  int bid = blockIdx.x;
  if (bid >= 1024) {
    // ---------------- conv path (no barriers, early return) ----------------
    int cb = bid - 1024;  // 512: b(1) | a(1) | pair(7 high); ntile = pair*2 + (tid>>8)
    int b = cb & 1;
    int a = (cb >> 1) & 1;
    int ntile = (cb >> 2) * 2 + (threadIdx.x >> 8);
    int t = threadIdx.x & 255;
    int dt = t >> 6;
    int lane = t & 63;
    int lo = lane & 15, g = lane >> 4;

    const __hip_bfloat16* fb = fhl + ((size_t)(a * BB + b) * NN + ntile * 16 + lo) * CH;
    bf16x8 ah0 = *reinterpret_cast<const bf16x8*>(fb + g * 8);
    bf16x8 ah1 = *reinterpret_cast<const bf16x8*>(fb + 32 + g * 8);
    bf16x8 al0 = *reinterpret_cast<const bf16x8*>(fb + FHALF + g * 8);
    bf16x8 al1 = *reinterpret_cast<const bf16x8*>(fb + FHALF + 32 + g * 8);

#pragma unroll
    for (int w = 0; w < 2; ++w) {
      const __hip_bfloat16* wb = wcb + w * 4096 + (dt * 16 + lo) * 64;
      bf16x8 wh0 = *reinterpret_cast<const bf16x8*>(wb + g * 8);
      bf16x8 wh1 = *reinterpret_cast<const bf16x8*>(wb + 32 + g * 8);
      bf16x8 wl0 = *reinterpret_cast<const bf16x8*>(wb + 8192 + g * 8);
      bf16x8 wl1 = *reinterpret_cast<const bf16x8*>(wb + 8192 + 32 + g * 8);
      float bv = cn[(w ? BT22_C : BT11_C) + dt * 16 + lo];
      f32x4 acc = {bv, bv, bv, bv};
      acc = __builtin_amdgcn_mfma_f32_16x16x32_bf16(ah0, wh0, acc, 0, 0, 0);
      acc = __builtin_amdgcn_mfma_f32_16x16x32_bf16(ah1, wh1, acc, 0, 0, 0);
      acc = __builtin_amdgcn_mfma_f32_16x16x32_bf16(al0, wh0, acc, 0, 0, 0);
      acc = __builtin_amdgcn_mfma_f32_16x16x32_bf16(al1, wh1, acc, 0, 0, 0);
      acc = __builtin_amdgcn_mfma_f32_16x16x32_bf16(ah0, wl0, acc, 0, 0, 0);
      acc = __builtin_amdgcn_mfma_f32_16x16x32_bf16(ah1, wl1, acc, 0, 0, 0);
      int sel = a ? (w ? 1 : 2) : (w ? 3 : 0);
      float* ob = fbuf + ((size_t)(sel * BB + b) * NN + ntile * 16 + g * 4) * CH + dt * 16 + lo;
      ob[0 * CH] = acc[0];
      ob[1 * CH] = acc[1];
      ob[2 * CH] = acc[2];
      ob[3 * CH] = acc[3];
    }
    return;
  }

  // ---------------- knn path ----------------
  __shared__ unsigned skc[16 * 8 * 9];  // cosine keys, 4.6 KB
  __shared__ unsigned ske[16 * 8 * 9];  // euclid keys, 4.6 KB
  __shared__ int cidx[2 * 16 * 16];     // [phase][query][16 cand]
  int b = bid & 1;
  int x = (bid >> 1) & 1;
  int qt = bid >> 2;
  int w = threadIdx.x >> 6;
  int lane = threadIdx.x & 63;
  int lo = lane & 15, g = lane >> 4;
  int q0 = qt * 16;
  int j0 = w * (NN / 8);
  size_t qbase = (size_t)(x * BB + b) * NN;
  size_t dbase = (size_t)((1 - x) * BB + b) * NN;

  const __hip_bfloat16* qb = knnb + (qbase + q0) * CH;
  bf16x8 qf0 = *reinterpret_cast<const bf16x8*>(qb + lo * CH + g * 8);
  bf16x8 qf1 = *reinterpret_cast<const bf16x8*>(qb + lo * CH + 32 + g * 8);
  const __hip_bfloat16* db = knnb + dbase * CH;
  const float4 q4 = xyzt[qbase + q0 + lo];
  const float4* dbx = xyzt + dbase;
  float tx = 2.f * q4.x, ty = 2.f * q4.y, tz = 2.f * q4.z;

  unsigned bc0[8], bc1[8], be0[8], be1[8];
#pragma unroll
  for (int k = 0; k < 8; ++k) { bc0[k] = 0u; bc1[k] = 0u; be0[k] = 0u; be1[k] = 0u; }

  auto STEP = [&](const bf16x8& A0, const bf16x8& A1, const float4& P0,
                  const float4& P1, const float4& P2, const float4& P3,
                  int rcv, unsigned (&bc)[8], unsigned (&be)[8]) {
    f32x4 acc = {0.f, 0.f, 0.f, 0.f};
    acc = __builtin_amdgcn_mfma_f32_16x16x32_bf16(A0, qf0, acc, 0, 0, 0);
    acc = __builtin_amdgcn_mfma_f32_16x16x32_bf16(A1, qf1, acc, 0, 0, 0);
    float v0 = fmaf(tx, P0.x, fmaf(ty, P0.y, fmaf(tz, P0.z, -P0.w)));
    float v1 = fmaf(tx, P1.x, fmaf(ty, P1.y, fmaf(tz, P1.z, -P1.w)));
    float v2 = fmaf(tx, P2.x, fmaf(ty, P2.y, fmaf(tz, P2.z, -P2.w)));
    float v3 = fmaf(tx, P3.x, fmaf(ty, P3.y, fmaf(tz, P3.z, -P3.w)));
    unsigned r = (unsigned)rcv;
    merge4(bc, (__float_as_uint(acc[0] + 4.0f) & 0xFFFFF000u) | r,
               (__float_as_uint(acc[1] + 4.0f) & 0xFFFFF000u) | (r - 1),
               (__float_as_uint(acc[2] + 4.0f) & 0xFFFFF000u) | (r - 2),
               (__float_as_uint(acc[3] + 4.0f) & 0xFFFFF000u) | (r - 3));
    merge4(be, (fmap(v0) & 0xFFFFF000u) | r,
               (fmap(v1) & 0xFFFFF000u) | (r - 1),
               (fmap(v2) & 0xFFFFF000u) | (r - 2),
               (fmap(v3) & 0xFFFFF000u) | (r - 3));
  };

  // ---- pipelined scan: 32 tiles, A=even / B=odd, one-tile prefetch ahead
  const __hip_bfloat16* arA = db + (size_t)(j0 + lo) * CH + g * 8;
  const __hip_bfloat16* arB = arA + 16 * CH;
  const float4* peA = dbx + j0 + g * 4;
  const float4* peB = peA + 16;
  int rc = 4095 - j0 - g * 4;

  bf16x8 aA0 = *reinterpret_cast<const bf16x8*>(arA);
  bf16x8 aA1 = *reinterpret_cast<const bf16x8*>(arA + 32);
  float4 pA0 = peA[0], pA1 = peA[1], pA2 = peA[2], pA3 = peA[3];

  for (int i = 0; i < 15; ++i) {
    bf16x8 aB0 = *reinterpret_cast<const bf16x8*>(arB);
    bf16x8 aB1 = *reinterpret_cast<const bf16x8*>(arB + 32);
    float4 pB0 = peB[0], pB1 = peB[1], pB2 = peB[2], pB3 = peB[3];
    STEP(aA0, aA1, pA0, pA1, pA2, pA3, rc, bc0, be0);
    arA += 32 * CH; peA += 32;
    aA0 = *reinterpret_cast<const bf16x8*>(arA);
    aA1 = *reinterpret_cast<const bf16x8*>(arA + 32);
    pA0 = peA[0]; pA1 = peA[1]; pA2 = peA[2]; pA3 = peA[3];
    STEP(aB0, aB1, pB0, pB1, pB2, pB3, rc - 16, bc1, be1);
    arB += 32 * CH; peB += 32;
    rc -= 32;
  }
  {
    bf16x8 aB0 = *reinterpret_cast<const bf16x8*>(arB);
    bf16x8 aB1 = *reinterpret_cast<const bf16x8*>(arB + 32);
    float4 pB0 = peB[0], pB1 = peB[1], pB2 = peB[2], pB3 = peB[3];
    STEP(aA0, aA1, pA0, pA1, pA2, pA3, rc, bc0, be0);
    STEP(aB0, aB1, pB0, pB1, pB2, pB3, rc - 16, bc1, be1);
  }
  merge88(bc0, bc1);
  merge88(be0, be1);
  // cross-group register merge: 32 substreams -> 8 (one per wave, per query)
  xmerge(bc0, 16); xmerge(bc0, 32);
  xmerge(be0, 16); xmerge(be0, 32);

  // ---- dump BOTH phases' keys, one barrier
  if (g == 0) {
#pragma unroll
    for (int k = 0; k < 8; ++k) {
      skc[(lo * 8 + k) * 9 + w] = bc0[k];
      ske[(lo * 8 + k) * 9 + w] = be0[k];
    }
  }
  __syncthreads();

  // ---- unified extraction: waves 0-3 cosine, 4-7 euclid; 4 queries/wave,
  //      16-lane groups (8 slots duplicated x2 within group)
  {
    int p = w >> 2;                          // 0 = cosine, 1 = euclid
    int qq = (w & 3) * 4 + (lane >> 4);      // this group's query (0..15)
    int sl = lane & 15;
    const unsigned* skp = p ? ske : skc;
    unsigned e[16];
#pragma unroll
    for (int k = 0; k < 8; ++k) e[k] = skp[(qq * 8 + k) * 9 + (sl & 7)];
#pragma unroll
    for (int k = 8; k < 16; ++k) e[k] = 0u;
#pragma unroll
    for (int s = 1; s < 8; s <<= 1) {
      unsigned f[16];
#pragma unroll
      for (int k = 0; k < 16; ++k) f[k] = (unsigned)__shfl_xor((int)e[k], s, 64);
#pragma unroll
      for (int i = 0; i < 16; ++i) e[i] = umaxu(e[i], f[15 - i]);
      casu(e[0], e[8]); casu(e[1], e[9]); casu(e[2], e[10]); casu(e[3], e[11]);
      casu(e[4], e[12]); casu(e[5], e[13]); casu(e[6], e[14]); casu(e[7], e[15]);
      casu(e[0], e[4]); casu(e[1], e[5]); casu(e[2], e[6]); casu(e[3], e[7]);
      casu(e[8], e[12]); casu(e[9], e[13]); casu(e[10], e[14]); casu(e[11], e[15]);
      casu(e[0], e[2]); casu(e[1], e[3]); casu(e[4], e[6]); casu(e[5], e[7]);
      casu(e[8], e[10]); casu(e[9], e[11]); casu(e[12], e[14]); casu(e[13], e[15]);
      casu(e[0], e[1]); casu(e[2], e[3]); casu(e[4], e[5]); casu(e[6], e[7]);
      casu(e[8], e[9]); casu(e[10], e[11]); casu(e[12], e[13]); casu(e[14], e[15]);
    }
    if (sl == 0) {
#pragma unroll
      for (int k = 0; k < 16; ++k) cidx[(p * 16 + qq) * 16 + k] = 4095 - (int)(e[k] & 4095u);
    }
    int idx = cidx[(p * 16 + qq) * 16 + sl];  // same-wave lockstep write->read
    float v;
    if (p == 0) {
      // cosine: exact f32 dot of normalized rows (one lane per candidate)
      const float4* qr = reinterpret_cast<const float4*>(knnt + (qbase + q0 + qq) * CH);
      const float4* dr = reinterpret_cast<const float4*>(knnt + (dbase + idx) * CH);
      v = 0.f;
#pragma unroll 4
      for (int cb = 0; cb < 16; ++cb) {
        float4 qv = qr[cb], dv = dr[cb];
        v += qv.x * dv.x + qv.y * dv.y + qv.z * dv.z + qv.w * dv.w;
      }
    } else {
      // euclid: exact f32 key = 2*q.p - |p|^2
      const float4 qx4 = xyzt[qbase + q0 + qq];
      float4 pp = xyzt[dbase + idx];
      v = fmaf(2.f * qx4.x, pp.x, fmaf(2.f * qx4.y, pp.y, fmaf(2.f * qx4.z, pp.z, -pp.w)));
    }
    // bitonic sort 16 distinct candidates desc by (v, idx asc); take first 8
    int ii = idx;
#pragma unroll
    for (int k = 2; k <= 16; k <<= 1) {
#pragma unroll
      for (int j = k >> 1; j >= 1; j >>= 1) {
        float ov = __shfl_xor(v, j, 64);
        int oi = __shfl_xor(ii, j, 64);
        bool ob = (ov > v) || (ov == v && oi < ii);
        bool want = (((sl & k) == 0) == ((sl & j) == 0));
        bool take = (want == ob);
        v = take ? ov : v;
        ii = take ? oi : ii;
      }
    }
    if (sl < 8) idxf[(qbase + q0 + qq) * 16 + p * 8 + sl] = ii;
  }
}

// ---- fused gather + pos-conv + 2x MFMA MLP + neighbor max. One wave per query.
// XCD-aware decode (x,b in low bid bits).
__global__ __launch_bounds__(256) void k_mlp(const float* __restrict__ fbuf,
                                             const float4* __restrict__ xyzt,
                                             const int* __restrict__ idxf,
                                             const float4* __restrict__ wp4,
                                             const __hip_bfloat16* __restrict__ wmb,
                                             const float* __restrict__ cn,
                                             float* __restrict__ out) {
  __shared__ __bf16 h1s[4 * 16 * 72];  // per-wave 16 rows x stride 72
  const int t = threadIdx.x;
  const int wv = t >> 6, L = t & 63;
  const int lo = L & 15, g = L >> 4;
  int bid = blockIdx.x;  // 4096: b(1) | x(1) | qt(10 high)
  const int b = bid & 1;
  const int x = (bid >> 1) & 1;
  const int qt = bid >> 2;
  const int q = qt * 4 + wv;

  bf16x8 w1f[4][2], w2f[4][2];
#pragma unroll
  for (int tt = 0; tt < 4; ++tt)
#pragma unroll
    for (int kc = 0; kc < 2; ++kc) {
      int e = tt * 16 + lo, c0 = kc * 32 + g * 8;
      w1f[tt][kc] = *reinterpret_cast<const bf16x8*>(wmb + e * 64 + c0);
      w2f[tt][kc] = *reinterpret_cast<const bf16x8*>(wmb + 4096 + e * 64 + c0);
    }

  const float* pq  = fbuf + ((size_t)((x ? 2 : 0) * BB + b)) * NN * CH;
  const float* pdb = fbuf + ((size_t)((x ? 3 : 1) * BB + b)) * NN * CH;
  const float4* qx  = xyzt + (size_t)(x * BB + b) * NN;
  const float4* dbx = xyzt + (size_t)((1 - x) * BB + b) * NN;

  const int m = lo;
  int jm = idxf[(((size_t)x * BB + b) * NN + q) * 16 + m];
  jm &= (NN - 1);
  const float4 q4 = qx[q];
  const float4 p4 = dbx[jm];
  const float dx = p4.x - q4.x, dy = p4.y - q4.y, dz = p4.z - q4.z;

  const float4* g2v = reinterpret_cast<const float4*>(pdb + (size_t)jm * CH);
  const float4* pqv = reinterpret_cast<const float4*>(pq + (size_t)q * CH);
  float hv[16];
  {
    float4 t0 = g2v[g * 2], t1 = g2v[g * 2 + 1], t2 = g2v[g * 2 + 8], t3 = g2v[g * 2 + 9];
    float4 u0 = pqv[g * 2], u1 = pqv[g * 2 + 1], u2 = pqv[g * 2 + 8], u3 = pqv[g * 2 + 9];
    hv[0] = t0.x + u0.x; hv[1] = t0.y + u0.y; hv[2] = t0.z + u0.z; hv[3] = t0.w + u0.w;
    hv[4] = t1.x + u1.x; hv[5] = t1.y + u1.y; hv[6] = t1.z + u1.z; hv[7] = t1.w + u1.w;
    hv[8] = t2.x + u2.x; hv[9] = t2.y + u2.y; hv[10] = t2.z + u2.z; hv[11] = t2.w + u2.w;
    hv[12] = t3.x + u3.x; hv[13] = t3.y + u3.y; hv[14] = t3.z + u3.z; hv[15] = t3.w + u3.w;
  }

  bf16x8 a0, a1;
#pragma unroll
  for (int kc = 0; kc < 2; ++kc) {
#pragma unroll
    for (int j = 0; j < 8; ++j) {
      int c = kc * 32 + g * 8 + j;
      float4 wp = wp4[c];
      float v = hv[kc * 8 + j] + wp.x * dx + wp.y * dy + wp.z * dz + wp.w;
      v = lrelu(v);
      if (kc == 0) a0[j] = (__bf16)v; else a1[j] = (__bf16)v;
    }
  }

  __bf16* hrow = h1s + wv * 16 * 72;
#pragma unroll
  for (int tt = 0; tt < 4; ++tt) {
    float bv = cn[BM1_C + tt * 16 + lo];
    f32x4 acc = {bv, bv, bv, bv};
    acc = __builtin_amdgcn_mfma_f32_16x16x32_bf16(a0, w1f[tt][0], acc, 0, 0, 0);
    acc = __builtin_amdgcn_mfma_f32_16x16x32_bf16(a1, w1f[tt][1], acc, 0, 0, 0);
#pragma unroll
    for (int r = 0; r < 4; ++r) {
      float v = lrelu(acc[r]);
      hrow[(g * 4 + r) * 72 + tt * 16 + lo] = (__bf16)v;
    }
  }
  __syncthreads();
  bf16x8 h1a = *reinterpret_cast<const bf16x8*>(hrow + m * 72 + g * 8);
  bf16x8 h1b = *reinterpret_cast<const bf16x8*>(hrow + m * 72 + 32 + g * 8);

  size_t obase = ((size_t)(x * BB + b) * CH) * NN;
#pragma unroll
  for (int tt = 0; tt < 4; ++tt) {
    float bv = cn[BM2_C + tt * 16 + lo];
    f32x4 acc = {bv, bv, bv, bv};
    acc = __builtin_amdgcn_mfma_f32_16x16x32_bf16(h1a, w2f[tt][0], acc, 0, 0, 0);
    acc = __builtin_amdgcn_mfma_f32_16x16x32_bf16(h1b, w2f[tt][1], acc, 0, 0, 0);
    float v = fmaxf(fmaxf(lrelu(acc[0]), lrelu(acc[1])), fmaxf(lrelu(acc[2]), lrelu(acc[3])));
    v = fmaxf(v, __shfl_xor(v, 16, 64));
    v = fmaxf(v, __shfl_xor(v, 32, 64));
    if (g == 0) out[obase + (size_t)(tt * 16 + lo) * NN + q] = v;
  }
}

// workspace layout (float units)
#define CN_OFF 0
#define FB_OFF ((size_t)CN_TOTAL)
#define KT_OFF (FB_OFF + (size_t)4 * BB * NN * CH)
#define XZ_OFF (KT_OFF + (size_t)2 * BB * NN * CH)
#define WP4_OFF (XZ_OFF + (size_t)2 * BB * NN * 4)
#define WMB_OFF (WP4_OFF + 256)
#define IDX_OFF (WMB_OFF + 4096)
#define FLAG_OFF (IDX_OFF + 262144)
#define KNB_OFF (FLAG_OFF + 4)
#define FHL_OFF (KNB_OFF + (size_t)BB * NN * CH)
#define WCB_OFF (FHL_OFF + (size_t)2 * BB * NN * CH)

extern "C" void kernel_launch(void* const* d_in, const int* in_sizes, int n_in,
                              void* d_out, int out_size, void* d_ws, size_t ws_size,
                              hipStream_t stream) {
  float* ws = (float*)d_ws;
  float* cn = ws + CN_OFF;

  k_ingest2<<<(CN_TOTAL / 4 + 255) / 256, 256, 0, stream>>>(
      d_in[0], d_in[1], d_in[2], d_in[3], d_in[4], d_in[5], d_in[6], d_in[7],
      d_in[8], d_in[9], d_in[10], d_in[11], d_in[12], d_in[13], d_in[14], d_in[15],
      cn);
  k_prep_all<<<257, 256, 0, stream>>>(cn, ws + KT_OFF, (__hip_bfloat16*)(ws + KNB_OFF),
                                      (__hip_bfloat16*)(ws + FHL_OFF),
                                      (__hip_bfloat16*)(ws + WMB_OFF),
                                      (float4*)(ws + XZ_OFF), (float4*)(ws + WP4_OFF),
                                      (__hip_bfloat16*)(ws + WCB_OFF));
  k_knncv<<<1536, 512, 0, stream>>>(
      (const __hip_bfloat16*)(ws + KNB_OFF), ws + KT_OFF, (const float4*)(ws + XZ_OFF),
      (const __hip_bfloat16*)(ws + FHL_OFF), (const __hip_bfloat16*)(ws + WCB_OFF),
      cn, (int*)(ws + IDX_OFF), ws + FB_OFF);
  k_mlp<<<2 * BB * (NN / 4), 256, 0, stream>>>(ws + FB_OFF, (const float4*)(ws + XZ_OFF),
                                               (const int*)(ws + IDX_OFF), (const float4*)(ws + WP4_OFF),
                                               (const __hip_bfloat16*)(ws + WMB_OFF), cn,
                                               (float*)d_out);
}

// Round 15
// 261.565 us; speedup vs baseline: 1.1059x; 1.0062x over previous
//
#include <hip/hip_runtime.h>
#include <hip/hip_bf16.h>

#define BB 2
#define NN 4096
#define CH 64

typedef __bf16 bf16x8 __attribute__((ext_vector_type(8)));
typedef float f32x4 __attribute__((ext_vector_type(4)));

__device__ __forceinline__ float lrelu(float v) { return fmaxf(v, 0.1f * v); }
__device__ __forceinline__ float tobf(const __hip_bfloat16& h) { return __bfloat162float(h); }

// canonical f32 input region offsets (element offsets within cn)
#define PC1_C 0
#define PC2_C 24576
#define F1_C 49152
#define F2_C 573440
#define K1_C 1097728
#define K2_C 1622016
#define WT11_C 2146304
#define BT11_C 2150400
#define WT22_C 2150464
#define BT22_C 2154560
#define WPOS_C 2154624
#define BPOS_C 2154816
#define WM1_C 2154880
#define BM1_C 2158976
#define WM2_C 2159040
#define BM2_C 2163136
#define CN_TOTAL 2163200

// fhl half offset (bf16 elements): fl mirror of fh
#define FHALF (2 * BB * NN * CH)

// ---- packed selection keys: (order-mapped f32 score, top 20 bits)<<12 | (4095-idx)
__device__ __forceinline__ unsigned fmap(float s) {
  unsigned u = __float_as_uint(s);
  return u ^ ((unsigned)((int)u >> 31) | 0x80000000u);
}

__device__ __forceinline__ unsigned umaxu(unsigned a, unsigned b) { return a > b ? a : b; }
__device__ __forceinline__ void casu(unsigned& a, unsigned& b) {
  unsigned mx = a > b ? a : b;
  unsigned mn = a > b ? b : a;
  a = mx; b = mn;
}

// bitonic-8 desc merge (input bitonic -> sorted desc)
__device__ __forceinline__ void bitonic8(unsigned bd[8]) {
  casu(bd[0], bd[4]); casu(bd[1], bd[5]); casu(bd[2], bd[6]); casu(bd[3], bd[7]);
  casu(bd[0], bd[2]); casu(bd[1], bd[3]); casu(bd[4], bd[6]); casu(bd[5], bd[7]);
  casu(bd[0], bd[1]); casu(bd[2], bd[3]); casu(bd[4], bd[5]); casu(bd[6], bd[7]);
}

// merge 4 new keys into sorted-desc-8 bd[] (branch-free)
__device__ __forceinline__ void merge4(unsigned bd[8], unsigned k0, unsigned k1,
                                       unsigned k2, unsigned k3) {
  casu(k0, k1); casu(k2, k3); casu(k0, k2); casu(k1, k3); casu(k1, k2);
  bd[4] = umaxu(bd[4], k3); bd[5] = umaxu(bd[5], k2);
  bd[6] = umaxu(bd[6], k1); bd[7] = umaxu(bd[7], k0);
  bitonic8(bd);
}

// top-8 of union of two sorted-desc-8 lists -> a[]
__device__ __forceinline__ void merge88(unsigned a[8], const unsigned b[8]) {
  a[0] = umaxu(a[0], b[7]); a[1] = umaxu(a[1], b[6]);
  a[2] = umaxu(a[2], b[5]); a[3] = umaxu(a[3], b[4]);
  a[4] = umaxu(a[4], b[3]); a[5] = umaxu(a[5], b[2]);
  a[6] = umaxu(a[6], b[1]); a[7] = umaxu(a[7], b[0]);
  bitonic8(a);
}

// cross-lane merge: a = top-8 of (a U partner(lane^m)'s a)
__device__ __forceinline__ void xmerge(unsigned a[8], int m) {
  unsigned t[8];
#pragma unroll
  for (int k = 0; k < 8; ++k) t[k] = (unsigned)__shfl_xor((int)a[k], m, 64);
  merge88(a, t);
}

// ---- per-wave dtype detect (reads pc1's first 8KB; L2-hot after first block)
__device__ __forceinline__ bool detect_f32(const unsigned short* __restrict__ pc1raw) {
  int lane = threadIdx.x & 63;
  const uint4* p4 = reinterpret_cast<const uint4*>(pc1raw);
  int bad = 0;
#pragma unroll
  for (int k = 0; k < 8; ++k) {
    uint4 v = p4[lane * 8 + k];
    bad += (((v.x >> 7) & 0xFF) >= 140) + (((v.x >> 23) & 0xFF) >= 140);
    bad += (((v.y >> 7) & 0xFF) >= 140) + (((v.y >> 23) & 0xFF) >= 140);
    bad += (((v.z >> 7) & 0xFF) >= 140) + (((v.z >> 23) & 0xFF) >= 140);
    bad += (((v.w >> 7) & 0xFF) >= 140) + (((v.w >> 23) & 0xFF) >= 140);
  }
#pragma unroll
  for (int s = 32; s; s >>= 1) bad += __shfl_xor(bad, s, 64);
  return bad > 16;  // true = inputs are float32
}

__device__ __forceinline__ float sani(float v) {
  if (!(v == v) || fabsf(v) > 1e30f) v = 0.f;
  return v;
}

// ---- ingest: detect fused (wave 0 + LDS broadcast), 4-wide vectorized.
__global__ __launch_bounds__(256) void k_ingest2(
    const void* p0, const void* p1, const void* p2, const void* p3,
    const void* p4, const void* p5, const void* p6, const void* p7,
    const void* p8, const void* p9, const void* p10, const void* p11,
    const void* p12, const void* p13, const void* p14, const void* p15,
    float* __restrict__ dst) {
  __shared__ int sflag;
  if (threadIdx.x < 64) {
    bool f = detect_f32((const unsigned short*)p0);
    if (threadIdx.x == 0) sflag = f ? 1 : 0;
  }
  __syncthreads();
  bool f32 = sflag != 0;

  const int cum[17] = {0, 24576, 49152, 573440, 1097728, 1622016, 2146304, 2150400,
                       2150464, 2154560, 2154624, 2154816, 2154880, 2158976, 2159040,
                       2163136, 2163200};
  const void* ptrs[16] = {p0, p1, p2, p3, p4, p5, p6, p7, p8, p9, p10, p11, p12, p13, p14, p15};
  size_t t4 = ((size_t)blockIdx.x * 256 + threadIdx.x) * 4;
  if (t4 >= (size_t)CN_TOTAL) return;
  int seg = 0, seg3 = 0;
  size_t t4e = t4 + 3;
#pragma unroll
  for (int i = 1; i < 16; ++i) {
    seg += (t4 >= (size_t)cum[i]) ? 1 : 0;
    seg3 += (t4e >= (size_t)cum[i]) ? 1 : 0;
  }
  if (seg == seg3 && t4e < (size_t)CN_TOTAL) {
    const void* p = ptrs[seg];
    size_t local = t4 - (size_t)cum[seg];
    float4 v;
    if (f32) {
      v = *reinterpret_cast<const float4*>((const float*)p + local);
    } else {
      ushort4 u = *reinterpret_cast<const ushort4*>((const unsigned short*)p + local);
      v.x = __uint_as_float((unsigned)u.x << 16);
      v.y = __uint_as_float((unsigned)u.y << 16);
      v.z = __uint_as_float((unsigned)u.z << 16);
      v.w = __uint_as_float((unsigned)u.w << 16);
    }
    v.x = sani(v.x); v.y = sani(v.y); v.z = sani(v.z); v.w = sani(v.w);
    *reinterpret_cast<float4*>(dst + t4) = v;
  } else {
#pragma unroll
    for (int i = 0; i < 4; ++i) {
      size_t t = t4 + i;
      if (t >= (size_t)CN_TOTAL) break;
      int s = 0;
#pragma unroll
      for (int k = 1; k < 16; ++k) s += (t >= (size_t)cum[k]) ? 1 : 0;
      const void* p = ptrs[s];
      size_t local = t - (size_t)cum[s];
      float v = f32 ? ((const float*)p)[local]
                    : __uint_as_float((unsigned)((const unsigned short*)p)[local] << 16);
      dst[t] = sani(v);
    }
  }
}

// ---- fused prep (one launch, cn-based): knn-normalize (single-pass, regs),
// feat hi/lo, Wm->bf16, xyz float4, wpos, conv-W hi/lo.
__global__ __launch_bounds__(256) void k_prep_all(const float* __restrict__ cn,
                                                  float* __restrict__ knnt,
                                                  __hip_bfloat16* __restrict__ knnb,
                                                  __hip_bfloat16* __restrict__ fhl,
                                                  __hip_bfloat16* __restrict__ wmb,
                                                  float4* __restrict__ xyzt,
                                                  float4* __restrict__ wp4,
                                                  __hip_bfloat16* __restrict__ wcb) {
  int bid = blockIdx.x;
  if (bid < 64) {
    int t = bid * 256 + threadIdx.x;  // 2*BB*NN
    int n = t & (NN - 1);
    int b = (t >> 12) & 1;
    int a = t >> 13;
    const float* col = cn + (a ? K2_C : K1_C) + (size_t)b * CH * NN + n;
    float vals[CH];  // fully unrolled -> static indices, stays in VGPRs
    float s = 0.f;
#pragma unroll
    for (int c = 0; c < CH; ++c) {
      float v = col[(size_t)c * NN];
      vals[c] = v;
      s += v * v;
    }
    float inv = 1.0f / sqrtf(s + 1e-8f);
    size_t row = (size_t)(a * BB + b) * NN + n;
    float* o = knnt + row * CH;
    __hip_bfloat16* ob = knnb + row * CH;
#pragma unroll
    for (int c = 0; c < CH; ++c) {
      float v = vals[c] * inv;
      o[c] = v;
      ob[c] = __float2bfloat16(v);
    }
  } else if (bid < 128) {
    int t = (bid - 64) * 256 + threadIdx.x;  // 2*BB*NN
    int n = t & (NN - 1);
    int b = (t >> 12) & 1;
    int a = t >> 13;
    const float* col = cn + (a ? F2_C : F1_C) + (size_t)b * CH * NN + n;
    __hip_bfloat16* oh = fhl + ((size_t)(a * BB + b) * NN + n) * CH;
    __hip_bfloat16* ol = oh + FHALF;
#pragma unroll
    for (int c = 0; c < CH; ++c) {
      float v = col[(size_t)c * NN];
      __hip_bfloat16 hi = __float2bfloat16(v);
      oh[c] = hi;
      ol[c] = __float2bfloat16(v - tobf(hi));
    }
  } else if (bid < 160) {
    int t = (bid - 128) * 256 + threadIdx.x;  // 8192
    float v = (t < 4096) ? cn[WM1_C + t] : cn[WM2_C + (t - 4096)];
    wmb[t] = __float2bfloat16(v);
  } else if (bid < 224) {
    int t = (bid - 160) * 256 + threadIdx.x;  // 2*BB*NN
    int n = t & (NN - 1);
    int b = (t >> 12) & 1;
    int a = t >> 13;
    const float* p = cn + (a ? PC2_C : PC1_C) + (size_t)b * 3 * NN + n;
    float x = p[0], y = p[NN], z = p[2 * NN];
    xyzt[(size_t)(a * BB + b) * NN + n] = make_float4(x, y, z, x * x + y * y + z * z);
  } else if (bid == 224) {
    int c = threadIdx.x;
    if (c < 64)
      wp4[c] = make_float4(cn[WPOS_C + 3 * c], cn[WPOS_C + 3 * c + 1],
                           cn[WPOS_C + 3 * c + 2], cn[BPOS_C + c]);
  } else {
    // conv weight hi/lo split: wcb[w][d*64+c] hi at [0,8192), lo at [8192,16384)
    int t = (bid - 225) * 256 + threadIdx.x;  // 8192 = 2 W x 4096
    int w = t >> 12, e = t & 4095;
    float v = cn[(w ? WT22_C : WT11_C) + e];
    __hip_bfloat16 hi = __float2bfloat16(v);
    __hip_bfloat16 lo = __float2bfloat16(v - tobf(hi));
    wcb[w * 4096 + e] = hi;
    wcb[8192 + w * 4096 + e] = lo;
  }
}

// ======================================================================
// k_knncv (unchanged from R17/R18, 119us verified): knn scan + parallel
// single-barrier extraction at (512,4); conv fused as bids 1024..1535.
// ======================================================================
__global__ __launch_bounds__(512, 4) void k_knncv(const __hip_bfloat16* __restrict__ knnb,
                                                  const float* __restrict__ knnt,
                                                  const float4* __restrict__ xyzt,
                                                  const __hip_bfloat16* __restrict__ fhl,
                                                  const __hip_bfloat16* __restrict__ wcb,
                                                  const float* __restrict__ cn,
                                                  int* __restrict__ idxf,
                                                  float* __restrict__ fbuf) {
  int bid = blockIdx.x;
  if (bid >= 1024) {
    // ---------------- conv path (no barriers, early return) ----------------
    int cb = bid - 1024;  // 512: b(1) | a(1) | pair(7 high); ntile = pair*2 + (tid>>8)
    int b = cb & 1;
    int a = (cb >> 1) & 1;
    int ntile = (cb >> 2) * 2 + (threadIdx.x >> 8);
    int t = threadIdx.x & 255;
    int dt = t >> 6;
    int lane = t & 63;
    int lo = lane & 15, g = lane >> 4;

    const __hip_bfloat16* fb = fhl + ((size_t)(a * BB + b) * NN + ntile * 16 + lo) * CH;
    bf16x8 ah0 = *reinterpret_cast<const bf16x8*>(fb + g * 8);
    bf16x8 ah1 = *reinterpret_cast<const bf16x8*>(fb + 32 + g * 8);
    bf16x8 al0 = *reinterpret_cast<const bf16x8*>(fb + FHALF + g * 8);
    bf16x8 al1 = *reinterpret_cast<const bf16x8*>(fb + FHALF + 32 + g * 8);

#pragma unroll
    for (int w = 0; w < 2; ++w) {
      const __hip_bfloat16* wb = wcb + w * 4096 + (dt * 16 + lo) * 64;
      bf16x8 wh0 = *reinterpret_cast<const bf16x8*>(wb + g * 8);
      bf16x8 wh1 = *reinterpret_cast<const bf16x8*>(wb + 32 + g * 8);
      bf16x8 wl0 = *reinterpret_cast<const bf16x8*>(wb + 8192 + g * 8);
      bf16x8 wl1 = *reinterpret_cast<const bf16x8*>(wb + 8192 + 32 + g * 8);
      float bv = cn[(w ? BT22_C : BT11_C) + dt * 16 + lo];
      f32x4 acc = {bv, bv, bv, bv};
      acc = __builtin_amdgcn_mfma_f32_16x16x32_bf16(ah0, wh0, acc, 0, 0, 0);
      acc = __builtin_amdgcn_mfma_f32_16x16x32_bf16(ah1, wh1, acc, 0, 0, 0);
      acc = __builtin_amdgcn_mfma_f32_16x16x32_bf16(al0, wh0, acc, 0, 0, 0);
      acc = __builtin_amdgcn_mfma_f32_16x16x32_bf16(al1, wh1, acc, 0, 0, 0);
      acc = __builtin_amdgcn_mfma_f32_16x16x32_bf16(ah0, wl0, acc, 0, 0, 0);
      acc = __builtin_amdgcn_mfma_f32_16x16x32_bf16(ah1, wl1, acc, 0, 0, 0);
      int sel = a ? (w ? 1 : 2) : (w ? 3 : 0);
      float* ob = fbuf + ((size_t)(sel * BB + b) * NN + ntile * 16 + g * 4) * CH + dt * 16 + lo;
      ob[0 * CH] = acc[0];
      ob[1 * CH] = acc[1];
      ob[2 * CH] = acc[2];
      ob[3 * CH] = acc[3];
    }
    return;
  }

  // ---------------- knn path ----------------
  __shared__ unsigned skc[16 * 8 * 9];  // cosine keys, 4.6 KB
  __shared__ unsigned ske[16 * 8 * 9];  // euclid keys, 4.6 KB
  __shared__ int cidx[2 * 16 * 16];     // [phase][query][16 cand]
  int b = bid & 1;
  int x = (bid >> 1) & 1;
  int qt = bid >> 2;
  int w = threadIdx.x >> 6;
  int lane = threadIdx.x & 63;
  int lo = lane & 15, g = lane >> 4;
  int q0 = qt * 16;
  int j0 = w * (NN / 8);
  size_t qbase = (size_t)(x * BB + b) * NN;
  size_t dbase = (size_t)((1 - x) * BB + b) * NN;

  const __hip_bfloat16* qb = knnb + (qbase + q0) * CH;
  bf16x8 qf0 = *reinterpret_cast<const bf16x8*>(qb + lo * CH + g * 8);
  bf16x8 qf1 = *reinterpret_cast<const bf16x8*>(qb + lo * CH + 32 + g * 8);
  const __hip_bfloat16* db = knnb + dbase * CH;
  const float4 q4 = xyzt[qbase + q0 + lo];
  const float4* dbx = xyzt + dbase;
  float tx = 2.f * q4.x, ty = 2.f * q4.y, tz = 2.f * q4.z;

  unsigned bc0[8], bc1[8], be0[8], be1[8];
#pragma unroll
  for (int k = 0; k < 8; ++k) { bc0[k] = 0u; bc1[k] = 0u; be0[k] = 0u; be1[k] = 0u; }

  auto STEP = [&](const bf16x8& A0, const bf16x8& A1, const float4& P0,
                  const float4& P1, const float4& P2, const float4& P3,
                  int rcv, unsigned (&bc)[8], unsigned (&be)[8]) {
    f32x4 acc = {0.f, 0.f, 0.f, 0.f};
    acc = __builtin_amdgcn_mfma_f32_16x16x32_bf16(A0, qf0, acc, 0, 0, 0);
    acc = __builtin_amdgcn_mfma_f32_16x16x32_bf16(A1, qf1, acc, 0, 0, 0);
    float v0 = fmaf(tx, P0.x, fmaf(ty, P0.y, fmaf(tz, P0.z, -P0.w)));
    float v1 = fmaf(tx, P1.x, fmaf(ty, P1.y, fmaf(tz, P1.z, -P1.w)));
    float v2 = fmaf(tx, P2.x, fmaf(ty, P2.y, fmaf(tz, P2.z, -P2.w)));
    float v3 = fmaf(tx, P3.x, fmaf(ty, P3.y, fmaf(tz, P3.z, -P3.w)));
    unsigned r = (unsigned)rcv;
    merge4(bc, (__float_as_uint(acc[0] + 4.0f) & 0xFFFFF000u) | r,
               (__float_as_uint(acc[1] + 4.0f) & 0xFFFFF000u) | (r - 1),
               (__float_as_uint(acc[2] + 4.0f) & 0xFFFFF000u) | (r - 2),
               (__float_as_uint(acc[3] + 4.0f) & 0xFFFFF000u) | (r - 3));
    merge4(be, (fmap(v0) & 0xFFFFF000u) | r,
               (fmap(v1) & 0xFFFFF000u) | (r - 1),
               (fmap(v2) & 0xFFFFF000u) | (r - 2),
               (fmap(v3) & 0xFFFFF000u) | (r - 3));
  };

  // ---- pipelined scan: 32 tiles, A=even / B=odd, one-tile prefetch ahead
  const __hip_bfloat16* arA = db + (size_t)(j0 + lo) * CH + g * 8;
  const __hip_bfloat16* arB = arA + 16 * CH;
  const float4* peA = dbx + j0 + g * 4;
  const float4* peB = peA + 16;
  int rc = 4095 - j0 - g * 4;

  bf16x8 aA0 = *reinterpret_cast<const bf16x8*>(arA);
  bf16x8 aA1 = *reinterpret_cast<const bf16x8*>(arA + 32);
  float4 pA0 = peA[0], pA1 = peA[1], pA2 = peA[2], pA3 = peA[3];

  for (int i = 0; i < 15; ++i) {
    bf16x8 aB0 = *reinterpret_cast<const bf16x8*>(arB);
    bf16x8 aB1 = *reinterpret_cast<const bf16x8*>(arB + 32);
    float4 pB0 = peB[0], pB1 = peB[1], pB2 = peB[2], pB3 = peB[3];
    STEP(aA0, aA1, pA0, pA1, pA2, pA3, rc, bc0, be0);
    arA += 32 * CH; peA += 32;
    aA0 = *reinterpret_cast<const bf16x8*>(arA);
    aA1 = *reinterpret_cast<const bf16x8*>(arA + 32);
    pA0 = peA[0]; pA1 = peA[1]; pA2 = peA[2]; pA3 = peA[3];
    STEP(aB0, aB1, pB0, pB1, pB2, pB3, rc - 16, bc1, be1);
    arB += 32 * CH; peB += 32;
    rc -= 32;
  }
  {
    bf16x8 aB0 = *reinterpret_cast<const bf16x8*>(arB);
    bf16x8 aB1 = *reinterpret_cast<const bf16x8*>(arB + 32);
    float4 pB0 = peB[0], pB1 = peB[1], pB2 = peB[2], pB3 = peB[3];
    STEP(aA0, aA1, pA0, pA1, pA2, pA3, rc, bc0, be0);
    STEP(aB0, aB1, pB0, pB1, pB2, pB3, rc - 16, bc1, be1);
  }
  merge88(bc0, bc1);
  merge88(be0, be1);
  // cross-group register merge: 32 substreams -> 8 (one per wave, per query)
  xmerge(bc0, 16); xmerge(bc0, 32);
  xmerge(be0, 16); xmerge(be0, 32);

  // ---- dump BOTH phases' keys, one barrier
  if (g == 0) {
#pragma unroll
    for (int k = 0; k < 8; ++k) {
      skc[(lo * 8 + k) * 9 + w] = bc0[k];
      ske[(lo * 8 + k) * 9 + w] = be0[k];
    }
  }
  __syncthreads();

  // ---- unified extraction: waves 0-3 cosine, 4-7 euclid; 4 queries/wave,
  //      16-lane groups (8 slots duplicated x2 within group)
  {
    int p = w >> 2;                          // 0 = cosine, 1 = euclid
    int qq = (w & 3) * 4 + (lane >> 4);      // this group's query (0..15)
    int sl = lane & 15;
    const unsigned* skp = p ? ske : skc;
    unsigned e[16];
#pragma unroll
    for (int k = 0; k < 8; ++k) e[k] = skp[(qq * 8 + k) * 9 + (sl & 7)];
#pragma unroll
    for (int k = 8; k < 16; ++k) e[k] = 0u;
#pragma unroll
    for (int s = 1; s < 8; s <<= 1) {
      unsigned f[16];
#pragma unroll
      for (int k = 0; k < 16; ++k) f[k] = (unsigned)__shfl_xor((int)e[k], s, 64);
#pragma unroll
      for (int i = 0; i < 16; ++i) e[i] = umaxu(e[i], f[15 - i]);
      casu(e[0], e[8]); casu(e[1], e[9]); casu(e[2], e[10]); casu(e[3], e[11]);
      casu(e[4], e[12]); casu(e[5], e[13]); casu(e[6], e[14]); casu(e[7], e[15]);
      casu(e[0], e[4]); casu(e[1], e[5]); casu(e[2], e[6]); casu(e[3], e[7]);
      casu(e[8], e[12]); casu(e[9], e[13]); casu(e[10], e[14]); casu(e[11], e[15]);
      casu(e[0], e[2]); casu(e[1], e[3]); casu(e[4], e[6]); casu(e[5], e[7]);
      casu(e[8], e[10]); casu(e[9], e[11]); casu(e[12], e[14]); casu(e[13], e[15]);
      casu(e[0], e[1]); casu(e[2], e[3]); casu(e[4], e[5]); casu(e[6], e[7]);
      casu(e[8], e[9]); casu(e[10], e[11]); casu(e[12], e[13]); casu(e[14], e[15]);
    }
    if (sl == 0) {
#pragma unroll
      for (int k = 0; k < 16; ++k) cidx[(p * 16 + qq) * 16 + k] = 4095 - (int)(e[k] & 4095u);
    }
    int idx = cidx[(p * 16 + qq) * 16 + sl];  // same-wave lockstep write->read
    float v;
    if (p == 0) {
      // cosine: exact f32 dot of normalized rows (one lane per candidate)
      const float4* qr = reinterpret_cast<const float4*>(knnt + (qbase + q0 + qq) * CH);
      const float4* dr = reinterpret_cast<const float4*>(knnt + (dbase + idx) * CH);
      v = 0.f;
#pragma unroll 4
      for (int cb = 0; cb < 16; ++cb) {
        float4 qv = qr[cb], dv = dr[cb];
        v += qv.x * dv.x + qv.y * dv.y + qv.z * dv.z + qv.w * dv.w;
      }
    } else {
      // euclid: exact f32 key = 2*q.p - |p|^2
      const float4 qx4 = xyzt[qbase + q0 + qq];
      float4 pp = xyzt[dbase + idx];
      v = fmaf(2.f * qx4.x, pp.x, fmaf(2.f * qx4.y, pp.y, fmaf(2.f * qx4.z, pp.z, -pp.w)));
    }
    // bitonic sort 16 distinct candidates desc by (v, idx asc); take first 8
    int ii = idx;
#pragma unroll
    for (int k = 2; k <= 16; k <<= 1) {
#pragma unroll
      for (int j = k >> 1; j >= 1; j >>= 1) {
        float ov = __shfl_xor(v, j, 64);
        int oi = __shfl_xor(ii, j, 64);
        bool ob = (ov > v) || (ov == v && oi < ii);
        bool want = (((sl & k) == 0) == ((sl & j) == 0));
        bool take = (want == ob);
        v = take ? ov : v;
        ii = take ? oi : ii;
      }
    }
    if (sl < 8) idxf[(qbase + q0 + qq) * 16 + p * 8 + sl] = ii;
  }
}

// ---- R19 k_mlp: gather-first + JIT weight loads (-48 resident VGPRs) +
// NO block barrier (each wave reads only its OWN h1s region; in-wave LDS
// write->read order is enforced by compiler lgkmcnt waits -- the old
// __syncthreads also forced a vmcnt(0) drain of all gathers, serializing
// them). XCD-aware decode (x,b in low bid bits).
__global__ __launch_bounds__(256) void k_mlp(const float* __restrict__ fbuf,
                                             const float4* __restrict__ xyzt,
                                             const int* __restrict__ idxf,
                                             const float4* __restrict__ wp4,
                                             const __hip_bfloat16* __restrict__ wmb,
                                             const float* __restrict__ cn,
                                             float* __restrict__ out) {
  __shared__ __bf16 h1s[4 * 16 * 72];  // per-wave 16 rows x stride 72
  const int t = threadIdx.x;
  const int wv = t >> 6, L = t & 63;
  const int lo = L & 15, g = L >> 4;
  int bid = blockIdx.x;  // 4096: b(1) | x(1) | qt(10 high)
  const int b = bid & 1;
  const int x = (bid >> 1) & 1;
  const int qt = bid >> 2;
  const int q = qt * 4 + wv;

  const float* pq  = fbuf + ((size_t)((x ? 2 : 0) * BB + b)) * NN * CH;
  const float* pdb = fbuf + ((size_t)((x ? 3 : 1) * BB + b)) * NN * CH;
  const float4* qx  = xyzt + (size_t)(x * BB + b) * NN;
  const float4* dbx = xyzt + (size_t)((1 - x) * BB + b) * NN;

  // ---- issue gathers FIRST (latency overlaps H0 build + weight loads)
  const int m = lo;
  int jm = idxf[(((size_t)x * BB + b) * NN + q) * 16 + m];
  jm &= (NN - 1);
  const float4* g2v = reinterpret_cast<const float4*>(pdb + (size_t)jm * CH);
  const float4* pqv = reinterpret_cast<const float4*>(pq + (size_t)q * CH);
  float4 t0 = g2v[g * 2], t1 = g2v[g * 2 + 1], t2 = g2v[g * 2 + 8], t3 = g2v[g * 2 + 9];
  float4 u0 = pqv[g * 2], u1 = pqv[g * 2 + 1], u2 = pqv[g * 2 + 8], u3 = pqv[g * 2 + 9];
  const float4 q4 = qx[q];
  const float4 p4 = dbx[jm];
  const float dx = p4.x - q4.x, dy = p4.y - q4.y, dz = p4.z - q4.z;

  float hv[16];
  hv[0] = t0.x + u0.x; hv[1] = t0.y + u0.y; hv[2] = t0.z + u0.z; hv[3] = t0.w + u0.w;
  hv[4] = t1.x + u1.x; hv[5] = t1.y + u1.y; hv[6] = t1.z + u1.z; hv[7] = t1.w + u1.w;
  hv[8] = t2.x + u2.x; hv[9] = t2.y + u2.y; hv[10] = t2.z + u2.z; hv[11] = t2.w + u2.w;
  hv[12] = t3.x + u3.x; hv[13] = t3.y + u3.y; hv[14] = t3.z + u3.z; hv[15] = t3.w + u3.w;

  // H0 built directly in A-fragment layout
  bf16x8 a0, a1;
#pragma unroll
  for (int kc = 0; kc < 2; ++kc) {
#pragma unroll
    for (int j = 0; j < 8; ++j) {
      int c = kc * 32 + g * 8 + j;
      float4 wp = wp4[c];
      float v = hv[kc * 8 + j] + wp.x * dx + wp.y * dy + wp.z * dz + wp.w;
      v = lrelu(v);
      if (kc == 0) a0[j] = (__bf16)v; else a1[j] = (__bf16)v;
    }
  }

  // layer 1 -> LDS (JIT weight loads; D-layout write, A-layout read)
  __bf16* hrow = h1s + wv * 16 * 72;
#pragma unroll
  for (int tt = 0; tt < 4; ++tt) {
    int e = tt * 16 + lo;
    bf16x8 wA = *reinterpret_cast<const bf16x8*>(wmb + e * 64 + g * 8);
    bf16x8 wB = *reinterpret_cast<const bf16x8*>(wmb + e * 64 + 32 + g * 8);
    float bv = cn[BM1_C + e];
    f32x4 acc = {bv, bv, bv, bv};
    acc = __builtin_amdgcn_mfma_f32_16x16x32_bf16(a0, wA, acc, 0, 0, 0);
    acc = __builtin_amdgcn_mfma_f32_16x16x32_bf16(a1, wB, acc, 0, 0, 0);
#pragma unroll
    for (int r = 0; r < 4; ++r) {
      float v = lrelu(acc[r]);
      hrow[(g * 4 + r) * 72 + e] = (__bf16)v;
    }
  }
  // no __syncthreads(): wave-private LDS region, in-wave order guaranteed
  bf16x8 h1a = *reinterpret_cast<const bf16x8*>(hrow + m * 72 + g * 8);
  bf16x8 h1b = *reinterpret_cast<const bf16x8*>(hrow + m * 72 + 32 + g * 8);

  // layer 2 + max over neighbors + store (f32), JIT weights
  size_t obase = ((size_t)(x * BB + b) * CH) * NN;
#pragma unroll
  for (int tt = 0; tt < 4; ++tt) {
    int e = tt * 16 + lo;
    bf16x8 wA = *reinterpret_cast<const bf16x8*>(wmb + 4096 + e * 64 + g * 8);
    bf16x8 wB = *reinterpret_cast<const bf16x8*>(wmb + 4096 + e * 64 + 32 + g * 8);
    float bv = cn[BM2_C + e];
    f32x4 acc = {bv, bv, bv, bv};
    acc = __builtin_amdgcn_mfma_f32_16x16x32_bf16(h1a, wA, acc, 0, 0, 0);
    acc = __builtin_amdgcn_mfma_f32_16x16x32_bf16(h1b, wB, acc, 0, 0, 0);
    float v = fmaxf(fmaxf(lrelu(acc[0]), lrelu(acc[1])), fmaxf(lrelu(acc[2]), lrelu(acc[3])));
    v = fmaxf(v, __shfl_xor(v, 16, 64));
    v = fmaxf(v, __shfl_xor(v, 32, 64));
    if (g == 0) out[obase + (size_t)e * NN + q] = v;
  }
}

// workspace layout (float units)
#define CN_OFF 0
#define FB_OFF ((size_t)CN_TOTAL)
#define KT_OFF (FB_OFF + (size_t)4 * BB * NN * CH)
#define XZ_OFF (KT_OFF + (size_t)2 * BB * NN * CH)
#define WP4_OFF (XZ_OFF + (size_t)2 * BB * NN * 4)
#define WMB_OFF (WP4_OFF + 256)
#define IDX_OFF (WMB_OFF + 4096)
#define FLAG_OFF (IDX_OFF + 262144)
#define KNB_OFF (FLAG_OFF + 4)
#define FHL_OFF (KNB_OFF + (size_t)BB * NN * CH)
#define WCB_OFF (FHL_OFF + (size_t)2 * BB * NN * CH)

extern "C" void kernel_launch(void* const* d_in, const int* in_sizes, int n_in,
                              void* d_out, int out_size, void* d_ws, size_t ws_size,
                              hipStream_t stream) {
  float* ws = (float*)d_ws;
  float* cn = ws + CN_OFF;

  k_ingest2<<<(CN_TOTAL / 4 + 255) / 256, 256, 0, stream>>>(
      d_in[0], d_in[1], d_in[2], d_in[3], d_in[4], d_in[5], d_in[6], d_in[7],
      d_in[8], d_in[9], d_in[10], d_in[11], d_in[12], d_in[13], d_in[14], d_in[15],
      cn);
  k_prep_all<<<257, 256, 0, stream>>>(cn, ws + KT_OFF, (__hip_bfloat16*)(ws + KNB_OFF),
                                      (__hip_bfloat16*)(ws + FHL_OFF),
                                      (__hip_bfloat16*)(ws + WMB_OFF),
                                      (float4*)(ws + XZ_OFF), (float4*)(ws + WP4_OFF),
                                      (__hip_bfloat16*)(ws + WCB_OFF));
  k_knncv<<<1536, 512, 0, stream>>>(
      (const __hip_bfloat16*)(ws + KNB_OFF), ws + KT_OFF, (const float4*)(ws + XZ_OFF),
      (const __hip_bfloat16*)(ws + FHL_OFF), (const __hip_bfloat16*)(ws + WCB_OFF),
      cn, (int*)(ws + IDX_OFF), ws + FB_OFF);
  k_mlp<<<2 * BB * (NN / 4), 256, 0, stream>>>(ws + FB_OFF, (const float4*)(ws + XZ_OFF),
                                               (const int*)(ws + IDX_OFF), (const float4*)(ws + WP4_OFF),
                                               (const __hip_bfloat16*)(ws + WMB_OFF), cn,
                                               (float*)d_out);
}

// Round 16
// 260.578 us; speedup vs baseline: 1.1100x; 1.0038x over previous
//
#include <hip/hip_runtime.h>
#include <hip/hip_bf16.h>

#define BB 2
#define NN 4096
#define CH 64

typedef __bf16 bf16x8 __attribute__((ext_vector_type(8)));
typedef float f32x4 __attribute__((ext_vector_type(4)));

__device__ __forceinline__ float lrelu(float v) { return fmaxf(v, 0.1f * v); }
__device__ __forceinline__ float tobf(const __hip_bfloat16& h) { return __bfloat162float(h); }

// canonical f32 input region offsets (element offsets within cn)
#define PC1_C 0
#define PC2_C 24576
#define F1_C 49152
#define F2_C 573440
#define K1_C 1097728
#define K2_C 1622016
#define WT11_C 2146304
#define BT11_C 2150400
#define WT22_C 2150464
#define BT22_C 2154560
#define WPOS_C 2154624
#define BPOS_C 2154816
#define WM1_C 2154880
#define BM1_C 2158976
#define WM2_C 2159040
#define BM2_C 2163136
#define CN_TOTAL 2163200

// fhl half offset (bf16 elements): fl mirror of fh
#define FHALF (2 * BB * NN * CH)

// ---- packed selection keys: (order-mapped f32 score, top 20 bits)<<12 | (4095-idx)
__device__ __forceinline__ unsigned fmap(float s) {
  unsigned u = __float_as_uint(s);
  return u ^ ((unsigned)((int)u >> 31) | 0x80000000u);
}

__device__ __forceinline__ unsigned umaxu(unsigned a, unsigned b) { return a > b ? a : b; }
__device__ __forceinline__ void casu(unsigned& a, unsigned& b) {
  unsigned mx = a > b ? a : b;
  unsigned mn = a > b ? b : a;
  a = mx; b = mn;
}

// bitonic-8 desc merge (input bitonic -> sorted desc)
__device__ __forceinline__ void bitonic8(unsigned bd[8]) {
  casu(bd[0], bd[4]); casu(bd[1], bd[5]); casu(bd[2], bd[6]); casu(bd[3], bd[7]);
  casu(bd[0], bd[2]); casu(bd[1], bd[3]); casu(bd[4], bd[6]); casu(bd[5], bd[7]);
  casu(bd[0], bd[1]); casu(bd[2], bd[3]); casu(bd[4], bd[5]); casu(bd[6], bd[7]);
}

// merge 4 new keys into sorted-desc-8 bd[] (branch-free)
__device__ __forceinline__ void merge4(unsigned bd[8], unsigned k0, unsigned k1,
                                       unsigned k2, unsigned k3) {
  casu(k0, k1); casu(k2, k3); casu(k0, k2); casu(k1, k3); casu(k1, k2);
  bd[4] = umaxu(bd[4], k3); bd[5] = umaxu(bd[5], k2);
  bd[6] = umaxu(bd[6], k1); bd[7] = umaxu(bd[7], k0);
  bitonic8(bd);
}

// top-8 of union of two sorted-desc-8 lists -> a[]
__device__ __forceinline__ void merge88(unsigned a[8], const unsigned b[8]) {
  a[0] = umaxu(a[0], b[7]); a[1] = umaxu(a[1], b[6]);
  a[2] = umaxu(a[2], b[5]); a[3] = umaxu(a[3], b[4]);
  a[4] = umaxu(a[4], b[3]); a[5] = umaxu(a[5], b[2]);
  a[6] = umaxu(a[6], b[1]); a[7] = umaxu(a[7], b[0]);
  bitonic8(a);
}

// cross-lane merge: a = top-8 of (a U partner(lane^m)'s a)
__device__ __forceinline__ void xmerge(unsigned a[8], int m) {
  unsigned t[8];
#pragma unroll
  for (int k = 0; k < 8; ++k) t[k] = (unsigned)__shfl_xor((int)a[k], m, 64);
  merge88(a, t);
}

// ---- per-wave dtype detect (reads pc1's first 8KB; L2-hot after first block)
__device__ __forceinline__ bool detect_f32(const unsigned short* __restrict__ pc1raw) {
  int lane = threadIdx.x & 63;
  const uint4* p4 = reinterpret_cast<const uint4*>(pc1raw);
  int bad = 0;
#pragma unroll
  for (int k = 0; k < 8; ++k) {
    uint4 v = p4[lane * 8 + k];
    bad += (((v.x >> 7) & 0xFF) >= 140) + (((v.x >> 23) & 0xFF) >= 140);
    bad += (((v.y >> 7) & 0xFF) >= 140) + (((v.y >> 23) & 0xFF) >= 140);
    bad += (((v.z >> 7) & 0xFF) >= 140) + (((v.z >> 23) & 0xFF) >= 140);
    bad += (((v.w >> 7) & 0xFF) >= 140) + (((v.w >> 23) & 0xFF) >= 140);
  }
#pragma unroll
  for (int s = 32; s; s >>= 1) bad += __shfl_xor(bad, s, 64);
  return bad > 16;  // true = inputs are float32
}

__device__ __forceinline__ float sani(float v) {
  if (!(v == v) || fabsf(v) > 1e30f) v = 0.f;
  return v;
}

// ---- ingest: detect fused (wave 0 + LDS broadcast), 4-wide vectorized.
__global__ __launch_bounds__(256) void k_ingest2(
    const void* p0, const void* p1, const void* p2, const void* p3,
    const void* p4, const void* p5, const void* p6, const void* p7,
    const void* p8, const void* p9, const void* p10, const void* p11,
    const void* p12, const void* p13, const void* p14, const void* p15,
    float* __restrict__ dst) {
  __shared__ int sflag;
  if (threadIdx.x < 64) {
    bool f = detect_f32((const unsigned short*)p0);
    if (threadIdx.x == 0) sflag = f ? 1 : 0;
  }
  __syncthreads();
  bool f32 = sflag != 0;

  const int cum[17] = {0, 24576, 49152, 573440, 1097728, 1622016, 2146304, 2150400,
                       2150464, 2154560, 2154624, 2154816, 2154880, 2158976, 2159040,
                       2163136, 2163200};
  const void* ptrs[16] = {p0, p1, p2, p3, p4, p5, p6, p7, p8, p9, p10, p11, p12, p13, p14, p15};
  size_t t4 = ((size_t)blockIdx.x * 256 + threadIdx.x) * 4;
  if (t4 >= (size_t)CN_TOTAL) return;
  int seg = 0, seg3 = 0;
  size_t t4e = t4 + 3;
#pragma unroll
  for (int i = 1; i < 16; ++i) {
    seg += (t4 >= (size_t)cum[i]) ? 1 : 0;
    seg3 += (t4e >= (size_t)cum[i]) ? 1 : 0;
  }
  if (seg == seg3 && t4e < (size_t)CN_TOTAL) {
    const void* p = ptrs[seg];
    size_t local = t4 - (size_t)cum[seg];
    float4 v;
    if (f32) {
      v = *reinterpret_cast<const float4*>((const float*)p + local);
    } else {
      ushort4 u = *reinterpret_cast<const ushort4*>((const unsigned short*)p + local);
      v.x = __uint_as_float((unsigned)u.x << 16);
      v.y = __uint_as_float((unsigned)u.y << 16);
      v.z = __uint_as_float((unsigned)u.z << 16);
      v.w = __uint_as_float((unsigned)u.w << 16);
    }
    v.x = sani(v.x); v.y = sani(v.y); v.z = sani(v.z); v.w = sani(v.w);
    *reinterpret_cast<float4*>(dst + t4) = v;
  } else {
#pragma unroll
    for (int i = 0; i < 4; ++i) {
      size_t t = t4 + i;
      if (t >= (size_t)CN_TOTAL) break;
      int s = 0;
#pragma unroll
      for (int k = 1; k < 16; ++k) s += (t >= (size_t)cum[k]) ? 1 : 0;
      const void* p = ptrs[s];
      size_t local = t - (size_t)cum[s];
      float v = f32 ? ((const float*)p)[local]
                    : __uint_as_float((unsigned)((const unsigned short*)p)[local] << 16);
      dst[t] = sani(v);
    }
  }
}

// ---- R20 fused prep: knn/feat sections now LDS-TRANSPOSED so the row-major
// outputs (knnt/knnb/fhl) get fully-coalesced writes (old pattern: each lane
// wrote its own 256B row -> every store scattered 64 lanes over 64 cache
// lines, 4x write transactions over 42MB).
// Block map: [0,256) knn | [256,512) feat | [512,544) wm | [544,608) xyz |
// 608 wpos | [609,641) wcb.
__global__ __launch_bounds__(256) void k_prep_all(const float* __restrict__ cn,
                                                  float* __restrict__ knnt,
                                                  __hip_bfloat16* __restrict__ knnb,
                                                  __hip_bfloat16* __restrict__ fhl,
                                                  __hip_bfloat16* __restrict__ wmb,
                                                  float4* __restrict__ xyzt,
                                                  float4* __restrict__ wp4,
                                                  __hip_bfloat16* __restrict__ wcb) {
  __shared__ float tile[64 * 65];  // [c][n], x65 pad: load conflict-free, col-read ~2-way
  int bid = blockIdx.x;
  int t = threadIdx.x;
  if (bid < 256) {
    // ---- knn-normalize, 64 points per block ----
    int P0 = bid * 64;                 // global point base
    int n0 = P0 & (NN - 1);
    int b = (P0 >> 12) & 1;
    int a = P0 >> 13;
    const float* base = cn + (a ? K2_C : K1_C) + (size_t)b * CH * NN + n0;
    int cq = t >> 6, n = t & 63;       // load: 4 channels/pass x 16 passes
#pragma unroll
    for (int i = 0; i < 16; ++i) {
      int c = i * 4 + cq;
      tile[c * 65 + n] = base[(size_t)c * NN + n];
    }
    __syncthreads();
    int nr = t >> 2, qr = t & 3;       // thread owns row nr, channels [qr*16, +16)
    float vals[16], s = 0.f;
#pragma unroll
    for (int k = 0; k < 16; ++k) {
      float v = tile[(qr * 16 + k) * 65 + nr];
      vals[k] = v;
      s += v * v;
    }
    s += __shfl_xor(s, 1, 64);
    s += __shfl_xor(s, 2, 64);
    float inv = 1.0f / sqrtf(s + 1e-8f);
    size_t row = (size_t)(a * BB + b) * NN + n0 + nr;
    float* o = knnt + row * CH + qr * 16;
    __hip_bfloat16* ob = knnb + row * CH + qr * 16;
#pragma unroll
    for (int k = 0; k < 16; ++k) {
      float v = vals[k] * inv;
      o[k] = v;
      ob[k] = __float2bfloat16(v);
    }
  } else if (bid < 512) {
    // ---- feat hi/lo split, 64 points per block ----
    int P0 = (bid - 256) * 64;
    int n0 = P0 & (NN - 1);
    int b = (P0 >> 12) & 1;
    int a = P0 >> 13;
    const float* base = cn + (a ? F2_C : F1_C) + (size_t)b * CH * NN + n0;
    int cq = t >> 6, n = t & 63;
#pragma unroll
    for (int i = 0; i < 16; ++i) {
      int c = i * 4 + cq;
      tile[c * 65 + n] = base[(size_t)c * NN + n];
    }
    __syncthreads();
    int nr = t >> 2, qr = t & 3;
    size_t row = (size_t)(a * BB + b) * NN + n0 + nr;
    __hip_bfloat16* oh = fhl + row * CH + qr * 16;
    __hip_bfloat16* ol = oh + FHALF;
#pragma unroll
    for (int k = 0; k < 16; ++k) {
      float v = tile[(qr * 16 + k) * 65 + nr];
      __hip_bfloat16 hi = __float2bfloat16(v);
      oh[k] = hi;
      ol[k] = __float2bfloat16(v - tobf(hi));
    }
  } else if (bid < 544) {
    int e = (bid - 512) * 256 + t;  // 8192
    float v = (e < 4096) ? cn[WM1_C + e] : cn[WM2_C + (e - 4096)];
    wmb[e] = __float2bfloat16(v);
  } else if (bid < 608) {
    int e = (bid - 544) * 256 + t;  // 2*BB*NN
    int n = e & (NN - 1);
    int b = (e >> 12) & 1;
    int a = e >> 13;
    const float* p = cn + (a ? PC2_C : PC1_C) + (size_t)b * 3 * NN + n;
    float x = p[0], y = p[NN], z = p[2 * NN];
    xyzt[(size_t)(a * BB + b) * NN + n] = make_float4(x, y, z, x * x + y * y + z * z);
  } else if (bid == 608) {
    int c = t;
    if (c < 64)
      wp4[c] = make_float4(cn[WPOS_C + 3 * c], cn[WPOS_C + 3 * c + 1],
                           cn[WPOS_C + 3 * c + 2], cn[BPOS_C + c]);
  } else {
    // conv weight hi/lo split: wcb[w][d*64+c] hi at [0,8192), lo at [8192,16384)
    int e = (bid - 609) * 256 + t;  // 8192 = 2 W x 4096
    int w = e >> 12, q = e & 4095;
    float v = cn[(w ? WT22_C : WT11_C) + q];
    __hip_bfloat16 hi = __float2bfloat16(v);
    __hip_bfloat16 lo = __float2bfloat16(v - tobf(hi));
    wcb[w * 4096 + q] = hi;
    wcb[8192 + w * 4096 + q] = lo;
  }
}

// ======================================================================
// k_knncv (unchanged from R17-R19, 119.6us verified): knn scan + parallel
// single-barrier extraction at (512,4); conv fused as bids 1024..1535.
// ======================================================================
__global__ __launch_bounds__(512, 4) void k_knncv(const __hip_bfloat16* __restrict__ knnb,
                                                  const float* __restrict__ knnt,
                                                  const float4* __restrict__ xyzt,
                                                  const __hip_bfloat16* __restrict__ fhl,
                                                  const __hip_bfloat16* __restrict__ wcb,
                                                  const float* __restrict__ cn,
                                                  int* __restrict__ idxf,
                                                  float* __restrict__ fbuf) {
  int bid = blockIdx.x;
  if (bid >= 1024) {
    // ---------------- conv path (no barriers, early return) ----------------
    int cb = bid - 1024;  // 512: b(1) | a(1) | pair(7 high); ntile = pair*2 + (tid>>8)
    int b = cb & 1;
    int a = (cb >> 1) & 1;
    int ntile = (cb >> 2) * 2 + (threadIdx.x >> 8);
    int t = threadIdx.x & 255;
    int dt = t >> 6;
    int lane = t & 63;
    int lo = lane & 15, g = lane >> 4;

    const __hip_bfloat16* fb = fhl + ((size_t)(a * BB + b) * NN + ntile * 16 + lo) * CH;
    bf16x8 ah0 = *reinterpret_cast<const bf16x8*>(fb + g * 8);
    bf16x8 ah1 = *reinterpret_cast<const bf16x8*>(fb + 32 + g * 8);
    bf16x8 al0 = *reinterpret_cast<const bf16x8*>(fb + FHALF + g * 8);
    bf16x8 al1 = *reinterpret_cast<const bf16x8*>(fb + FHALF + 32 + g * 8);

#pragma unroll
    for (int w = 0; w < 2; ++w) {
      const __hip_bfloat16* wb = wcb + w * 4096 + (dt * 16 + lo) * 64;
      bf16x8 wh0 = *reinterpret_cast<const bf16x8*>(wb + g * 8);
      bf16x8 wh1 = *reinterpret_cast<const bf16x8*>(wb + 32 + g * 8);
      bf16x8 wl0 = *reinterpret_cast<const bf16x8*>(wb + 8192 + g * 8);
      bf16x8 wl1 = *reinterpret_cast<const bf16x8*>(wb + 8192 + 32 + g * 8);
      float bv = cn[(w ? BT22_C : BT11_C) + dt * 16 + lo];
      f32x4 acc = {bv, bv, bv, bv};
      acc = __builtin_amdgcn_mfma_f32_16x16x32_bf16(ah0, wh0, acc, 0, 0, 0);
      acc = __builtin_amdgcn_mfma_f32_16x16x32_bf16(ah1, wh1, acc, 0, 0, 0);
      acc = __builtin_amdgcn_mfma_f32_16x16x32_bf16(al0, wh0, acc, 0, 0, 0);
      acc = __builtin_amdgcn_mfma_f32_16x16x32_bf16(al1, wh1, acc, 0, 0, 0);
      acc = __builtin_amdgcn_mfma_f32_16x16x32_bf16(ah0, wl0, acc, 0, 0, 0);
      acc = __builtin_amdgcn_mfma_f32_16x16x32_bf16(ah1, wl1, acc, 0, 0, 0);
      int sel = a ? (w ? 1 : 2) : (w ? 3 : 0);
      float* ob = fbuf + ((size_t)(sel * BB + b) * NN + ntile * 16 + g * 4) * CH + dt * 16 + lo;
      ob[0 * CH] = acc[0];
      ob[1 * CH] = acc[1];
      ob[2 * CH] = acc[2];
      ob[3 * CH] = acc[3];
    }
    return;
  }

  // ---------------- knn path ----------------
  __shared__ unsigned skc[16 * 8 * 9];  // cosine keys, 4.6 KB
  __shared__ unsigned ske[16 * 8 * 9];  // euclid keys, 4.6 KB
  __shared__ int cidx[2 * 16 * 16];     // [phase][query][16 cand]
  int b = bid & 1;
  int x = (bid >> 1) & 1;
  int qt = bid >> 2;
  int w = threadIdx.x >> 6;
  int lane = threadIdx.x & 63;
  int lo = lane & 15, g = lane >> 4;
  int q0 = qt * 16;
  int j0 = w * (NN / 8);
  size_t qbase = (size_t)(x * BB + b) * NN;
  size_t dbase = (size_t)((1 - x) * BB + b) * NN;

  const __hip_bfloat16* qb = knnb + (qbase + q0) * CH;
  bf16x8 qf0 = *reinterpret_cast<const bf16x8*>(qb + lo * CH + g * 8);
  bf16x8 qf1 = *reinterpret_cast<const bf16x8*>(qb + lo * CH + 32 + g * 8);
  const __hip_bfloat16* db = knnb + dbase * CH;
  const float4 q4 = xyzt[qbase + q0 + lo];
  const float4* dbx = xyzt + dbase;
  float tx = 2.f * q4.x, ty = 2.f * q4.y, tz = 2.f * q4.z;

  unsigned bc0[8], bc1[8], be0[8], be1[8];
#pragma unroll
  for (int k = 0; k < 8; ++k) { bc0[k] = 0u; bc1[k] = 0u; be0[k] = 0u; be1[k] = 0u; }

  auto STEP = [&](const bf16x8& A0, const bf16x8& A1, const float4& P0,
                  const float4& P1, const float4& P2, const float4& P3,
                  int rcv, unsigned (&bc)[8], unsigned (&be)[8]) {
    f32x4 acc = {0.f, 0.f, 0.f, 0.f};
    acc = __builtin_amdgcn_mfma_f32_16x16x32_bf16(A0, qf0, acc, 0, 0, 0);
    acc = __builtin_amdgcn_mfma_f32_16x16x32_bf16(A1, qf1, acc, 0, 0, 0);
    float v0 = fmaf(tx, P0.x, fmaf(ty, P0.y, fmaf(tz, P0.z, -P0.w)));
    float v1 = fmaf(tx, P1.x, fmaf(ty, P1.y, fmaf(tz, P1.z, -P1.w)));
    float v2 = fmaf(tx, P2.x, fmaf(ty, P2.y, fmaf(tz, P2.z, -P2.w)));
    float v3 = fmaf(tx, P3.x, fmaf(ty, P3.y, fmaf(tz, P3.z, -P3.w)));
    unsigned r = (unsigned)rcv;
    merge4(bc, (__float_as_uint(acc[0] + 4.0f) & 0xFFFFF000u) | r,
               (__float_as_uint(acc[1] + 4.0f) & 0xFFFFF000u) | (r - 1),
               (__float_as_uint(acc[2] + 4.0f) & 0xFFFFF000u) | (r - 2),
               (__float_as_uint(acc[3] + 4.0f) & 0xFFFFF000u) | (r - 3));
    merge4(be, (fmap(v0) & 0xFFFFF000u) | r,
               (fmap(v1) & 0xFFFFF000u) | (r - 1),
               (fmap(v2) & 0xFFFFF000u) | (r - 2),
               (fmap(v3) & 0xFFFFF000u) | (r - 3));
  };

  // ---- pipelined scan: 32 tiles, A=even / B=odd, one-tile prefetch ahead
  const __hip_bfloat16* arA = db + (size_t)(j0 + lo) * CH + g * 8;
  const __hip_bfloat16* arB = arA + 16 * CH;
  const float4* peA = dbx + j0 + g * 4;
  const float4* peB = peA + 16;
  int rc = 4095 - j0 - g * 4;

  bf16x8 aA0 = *reinterpret_cast<const bf16x8*>(arA);
  bf16x8 aA1 = *reinterpret_cast<const bf16x8*>(arA + 32);
  float4 pA0 = peA[0], pA1 = peA[1], pA2 = peA[2], pA3 = peA[3];

  for (int i = 0; i < 15; ++i) {
    bf16x8 aB0 = *reinterpret_cast<const bf16x8*>(arB);
    bf16x8 aB1 = *reinterpret_cast<const bf16x8*>(arB + 32);
    float4 pB0 = peB[0], pB1 = peB[1], pB2 = peB[2], pB3 = peB[3];
    STEP(aA0, aA1, pA0, pA1, pA2, pA3, rc, bc0, be0);
    arA += 32 * CH; peA += 32;
    aA0 = *reinterpret_cast<const bf16x8*>(arA);
    aA1 = *reinterpret_cast<const bf16x8*>(arA + 32);
    pA0 = peA[0]; pA1 = peA[1]; pA2 = peA[2]; pA3 = peA[3];
    STEP(aB0, aB1, pB0, pB1, pB2, pB3, rc - 16, bc1, be1);
    arB += 32 * CH; peB += 32;
    rc -= 32;
  }
  {
    bf16x8 aB0 = *reinterpret_cast<const bf16x8*>(arB);
    bf16x8 aB1 = *reinterpret_cast<const bf16x8*>(arB + 32);
    float4 pB0 = peB[0], pB1 = peB[1], pB2 = peB[2], pB3 = peB[3];
    STEP(aA0, aA1, pA0, pA1, pA2, pA3, rc, bc0, be0);
    STEP(aB0, aB1, pB0, pB1, pB2, pB3, rc - 16, bc1, be1);
  }
  merge88(bc0, bc1);
  merge88(be0, be1);
  // cross-group register merge: 32 substreams -> 8 (one per wave, per query)
  xmerge(bc0, 16); xmerge(bc0, 32);
  xmerge(be0, 16); xmerge(be0, 32);

  // ---- dump BOTH phases' keys, one barrier
  if (g == 0) {
#pragma unroll
    for (int k = 0; k < 8; ++k) {
      skc[(lo * 8 + k) * 9 + w] = bc0[k];
      ske[(lo * 8 + k) * 9 + w] = be0[k];
    }
  }
  __syncthreads();

  // ---- unified extraction: waves 0-3 cosine, 4-7 euclid; 4 queries/wave,
  //      16-lane groups (8 slots duplicated x2 within group)
  {
    int p = w >> 2;                          // 0 = cosine, 1 = euclid
    int qq = (w & 3) * 4 + (lane >> 4);      // this group's query (0..15)
    int sl = lane & 15;
    const unsigned* skp = p ? ske : skc;
    unsigned e[16];
#pragma unroll
    for (int k = 0; k < 8; ++k) e[k] = skp[(qq * 8 + k) * 9 + (sl & 7)];
#pragma unroll
    for (int k = 8; k < 16; ++k) e[k] = 0u;
#pragma unroll
    for (int s = 1; s < 8; s <<= 1) {
      unsigned f[16];
#pragma unroll
      for (int k = 0; k < 16; ++k) f[k] = (unsigned)__shfl_xor((int)e[k], s, 64);
#pragma unroll
      for (int i = 0; i < 16; ++i) e[i] = umaxu(e[i], f[15 - i]);
      casu(e[0], e[8]); casu(e[1], e[9]); casu(e[2], e[10]); casu(e[3], e[11]);
      casu(e[4], e[12]); casu(e[5], e[13]); casu(e[6], e[14]); casu(e[7], e[15]);
      casu(e[0], e[4]); casu(e[1], e[5]); casu(e[2], e[6]); casu(e[3], e[7]);
      casu(e[8], e[12]); casu(e[9], e[13]); casu(e[10], e[14]); casu(e[11], e[15]);
      casu(e[0], e[2]); casu(e[1], e[3]); casu(e[4], e[6]); casu(e[5], e[7]);
      casu(e[8], e[10]); casu(e[9], e[11]); casu(e[12], e[14]); casu(e[13], e[15]);
      casu(e[0], e[1]); casu(e[2], e[3]); casu(e[4], e[5]); casu(e[6], e[7]);
      casu(e[8], e[9]); casu(e[10], e[11]); casu(e[12], e[13]); casu(e[14], e[15]);
    }
    if (sl == 0) {
#pragma unroll
      for (int k = 0; k < 16; ++k) cidx[(p * 16 + qq) * 16 + k] = 4095 - (int)(e[k] & 4095u);
    }
    int idx = cidx[(p * 16 + qq) * 16 + sl];  // same-wave lockstep write->read
    float v;
    if (p == 0) {
      // cosine: exact f32 dot of normalized rows (one lane per candidate)
      const float4* qr = reinterpret_cast<const float4*>(knnt + (qbase + q0 + qq) * CH);
      const float4* dr = reinterpret_cast<const float4*>(knnt + (dbase + idx) * CH);
      v = 0.f;
#pragma unroll 4
      for (int cb = 0; cb < 16; ++cb) {
        float4 qv = qr[cb], dv = dr[cb];
        v += qv.x * dv.x + qv.y * dv.y + qv.z * dv.z + qv.w * dv.w;
      }
    } else {
      // euclid: exact f32 key = 2*q.p - |p|^2
      const float4 qx4 = xyzt[qbase + q0 + qq];
      float4 pp = xyzt[dbase + idx];
      v = fmaf(2.f * qx4.x, pp.x, fmaf(2.f * qx4.y, pp.y, fmaf(2.f * qx4.z, pp.z, -pp.w)));
    }
    // bitonic sort 16 distinct candidates desc by (v, idx asc); take first 8
    int ii = idx;
#pragma unroll
    for (int k = 2; k <= 16; k <<= 1) {
#pragma unroll
      for (int j = k >> 1; j >= 1; j >>= 1) {
        float ov = __shfl_xor(v, j, 64);
        int oi = __shfl_xor(ii, j, 64);
        bool ob = (ov > v) || (ov == v && oi < ii);
        bool want = (((sl & k) == 0) == ((sl & j) == 0));
        bool take = (want == ob);
        v = take ? ov : v;
        ii = take ? oi : ii;
      }
    }
    if (sl < 8) idxf[(qbase + q0 + qq) * 16 + p * 8 + sl] = ii;
  }
}

// ---- k_mlp (unchanged from R19): gather-first + JIT weights, no barrier.
__global__ __launch_bounds__(256) void k_mlp(const float* __restrict__ fbuf,
                                             const float4* __restrict__ xyzt,
                                             const int* __restrict__ idxf,
                                             const float4* __restrict__ wp4,
                                             const __hip_bfloat16* __restrict__ wmb,
                                             const float* __restrict__ cn,
                                             float* __restrict__ out) {
  __shared__ __bf16 h1s[4 * 16 * 72];  // per-wave 16 rows x stride 72
  const int t = threadIdx.x;
  const int wv = t >> 6, L = t & 63;
  const int lo = L & 15, g = L >> 4;
  int bid = blockIdx.x;  // 4096: b(1) | x(1) | qt(10 high)
  const int b = bid & 1;
  const int x = (bid >> 1) & 1;
  const int qt = bid >> 2;
  const int q = qt * 4 + wv;

  const float* pq  = fbuf + ((size_t)((x ? 2 : 0) * BB + b)) * NN * CH;
  const float* pdb = fbuf + ((size_t)((x ? 3 : 1) * BB + b)) * NN * CH;
  const float4* qx  = xyzt + (size_t)(x * BB + b) * NN;
  const float4* dbx = xyzt + (size_t)((1 - x) * BB + b) * NN;

  const int m = lo;
  int jm = idxf[(((size_t)x * BB + b) * NN + q) * 16 + m];
  jm &= (NN - 1);
  const float4* g2v = reinterpret_cast<const float4*>(pdb + (size_t)jm * CH);
  const float4* pqv = reinterpret_cast<const float4*>(pq + (size_t)q * CH);
  float4 t0 = g2v[g * 2], t1 = g2v[g * 2 + 1], t2 = g2v[g * 2 + 8], t3 = g2v[g * 2 + 9];
  float4 u0 = pqv[g * 2], u1 = pqv[g * 2 + 1], u2 = pqv[g * 2 + 8], u3 = pqv[g * 2 + 9];
  const float4 q4 = qx[q];
  const float4 p4 = dbx[jm];
  const float dx = p4.x - q4.x, dy = p4.y - q4.y, dz = p4.z - q4.z;

  float hv[16];
  hv[0] = t0.x + u0.x; hv[1] = t0.y + u0.y; hv[2] = t0.z + u0.z; hv[3] = t0.w + u0.w;
  hv[4] = t1.x + u1.x; hv[5] = t1.y + u1.y; hv[6] = t1.z + u1.z; hv[7] = t1.w + u1.w;
  hv[8] = t2.x + u2.x; hv[9] = t2.y + u2.y; hv[10] = t2.z + u2.z; hv[11] = t2.w + u2.w;
  hv[12] = t3.x + u3.x; hv[13] = t3.y + u3.y; hv[14] = t3.z + u3.z; hv[15] = t3.w + u3.w;

  bf16x8 a0, a1;
#pragma unroll
  for (int kc = 0; kc < 2; ++kc) {
#pragma unroll
    for (int j = 0; j < 8; ++j) {
      int c = kc * 32 + g * 8 + j;
      float4 wp = wp4[c];
      float v = hv[kc * 8 + j] + wp.x * dx + wp.y * dy + wp.z * dz + wp.w;
      v = lrelu(v);
      if (kc == 0) a0[j] = (__bf16)v; else a1[j] = (__bf16)v;
    }
  }

  __bf16* hrow = h1s + wv * 16 * 72;
#pragma unroll
  for (int tt = 0; tt < 4; ++tt) {
    int e = tt * 16 + lo;
    bf16x8 wA = *reinterpret_cast<const bf16x8*>(wmb + e * 64 + g * 8);
    bf16x8 wB = *reinterpret_cast<const bf16x8*>(wmb + e * 64 + 32 + g * 8);
    float bv = cn[BM1_C + e];
    f32x4 acc = {bv, bv, bv, bv};
    acc = __builtin_amdgcn_mfma_f32_16x16x32_bf16(a0, wA, acc, 0, 0, 0);
    acc = __builtin_amdgcn_mfma_f32_16x16x32_bf16(a1, wB, acc, 0, 0, 0);
#pragma unroll
    for (int r = 0; r < 4; ++r) {
      float v = lrelu(acc[r]);
      hrow[(g * 4 + r) * 72 + e] = (__bf16)v;
    }
  }
  // no __syncthreads(): wave-private LDS region, in-wave order guaranteed
  bf16x8 h1a = *reinterpret_cast<const bf16x8*>(hrow + m * 72 + g * 8);
  bf16x8 h1b = *reinterpret_cast<const bf16x8*>(hrow + m * 72 + 32 + g * 8);

  size_t obase = ((size_t)(x * BB + b) * CH) * NN;
#pragma unroll
  for (int tt = 0; tt < 4; ++tt) {
    int e = tt * 16 + lo;
    bf16x8 wA = *reinterpret_cast<const bf16x8*>(wmb + 4096 + e * 64 + g * 8);
    bf16x8 wB = *reinterpret_cast<const bf16x8*>(wmb + 4096 + e * 64 + 32 + g * 8);
    float bv = cn[BM2_C + e];
    f32x4 acc = {bv, bv, bv, bv};
    acc = __builtin_amdgcn_mfma_f32_16x16x32_bf16(h1a, wA, acc, 0, 0, 0);
    acc = __builtin_amdgcn_mfma_f32_16x16x32_bf16(h1b, wB, acc, 0, 0, 0);
    float v = fmaxf(fmaxf(lrelu(acc[0]), lrelu(acc[1])), fmaxf(lrelu(acc[2]), lrelu(acc[3])));
    v = fmaxf(v, __shfl_xor(v, 16, 64));
    v = fmaxf(v, __shfl_xor(v, 32, 64));
    if (g == 0) out[obase + (size_t)e * NN + q] = v;
  }
}

// workspace layout (float units)
#define CN_OFF 0
#define FB_OFF ((size_t)CN_TOTAL)
#define KT_OFF (FB_OFF + (size_t)4 * BB * NN * CH)
#define XZ_OFF (KT_OFF + (size_t)2 * BB * NN * CH)
#define WP4_OFF (XZ_OFF + (size_t)2 * BB * NN * 4)
#define WMB_OFF (WP4_OFF + 256)
#define IDX_OFF (WMB_OFF + 4096)
#define FLAG_OFF (IDX_OFF + 262144)
#define KNB_OFF (FLAG_OFF + 4)
#define FHL_OFF (KNB_OFF + (size_t)BB * NN * CH)
#define WCB_OFF (FHL_OFF + (size_t)2 * BB * NN * CH)

extern "C" void kernel_launch(void* const* d_in, const int* in_sizes, int n_in,
                              void* d_out, int out_size, void* d_ws, size_t ws_size,
                              hipStream_t stream) {
  float* ws = (float*)d_ws;
  float* cn = ws + CN_OFF;

  k_ingest2<<<(CN_TOTAL / 4 + 255) / 256, 256, 0, stream>>>(
      d_in[0], d_in[1], d_in[2], d_in[3], d_in[4], d_in[5], d_in[6], d_in[7],
      d_in[8], d_in[9], d_in[10], d_in[11], d_in[12], d_in[13], d_in[14], d_in[15],
      cn);
  k_prep_all<<<641, 256, 0, stream>>>(cn, ws + KT_OFF, (__hip_bfloat16*)(ws + KNB_OFF),
                                      (__hip_bfloat16*)(ws + FHL_OFF),
                                      (__hip_bfloat16*)(ws + WMB_OFF),
                                      (float4*)(ws + XZ_OFF), (float4*)(ws + WP4_OFF),
                                      (__hip_bfloat16*)(ws + WCB_OFF));
  k_knncv<<<1536, 512, 0, stream>>>(
      (const __hip_bfloat16*)(ws + KNB_OFF), ws + KT_OFF, (const float4*)(ws + XZ_OFF),
      (const __hip_bfloat16*)(ws + FHL_OFF), (const __hip_bfloat16*)(ws + WCB_OFF),
      cn, (int*)(ws + IDX_OFF), ws + FB_OFF);
  k_mlp<<<2 * BB * (NN / 4), 256, 0, stream>>>(ws + FB_OFF, (const float4*)(ws + XZ_OFF),
                                               (const int*)(ws + IDX_OFF), (const float4*)(ws + WP4_OFF),
                                               (const __hip_bfloat16*)(ws + WMB_OFF), cn,
                                               (float*)d_out);
}